// Round 5
// baseline (755.704 us; speedup 1.0000x reference)
//
#include <hip/hip_runtime.h>
#include <hip/hip_cooperative_groups.h>

namespace cg = cooperative_groups;

typedef unsigned long long u64;
typedef unsigned int u32;
typedef unsigned short u16;

#define N_PTS 32768
#define M_PTS 8192
#define C_IN 6
#define H_DIM 64

#define G 6
#define NCELL 216
#define NCELL_T 864
#define CW (1.0f/3.0f)

#define NBLK 512
#define CAP 128
#define KTGT 52.0f

#define TL0 0.0494f
#define TL1 0.0740f
#define TL2 0.1110f
#define TL3 0.1736f
#define TL4 0.2600f
#define TL5 0.4000f

// ws layout (bytes):
// 0      : stats1[128]f      (zeroed)
// 512    : stats2[128]f      (zeroed)
// 1024   : gcount[864]u32    (zeroed)  -> 4480
// 4480   : accum[5]double    (zeroed)  -> 4520
// 4520   : cellq u32         (zeroed)  -> 4524  (memset 0..4544)
// 4544   : cellstart[865]u32 -> 8004 pad 8008
// 8008   : cellptr[864]u32   -> 11464 pad 11472
// 11472  : S[32768]f         -> 142544
// 142544 : P4s[32768]float4  -> 666832
// 666832 : meta16[32768]u16  -> 732368
// 732368 : pcell[32768]u16   -> 797904

__device__ __forceinline__ float gelu_exact(float x) {
    return 0.5f * x * (1.0f + erff(x * 0.70710678118654752f));
}
__device__ __forceinline__ float sigmoidf_(float x) {
    return 1.0f / (1.0f + expf(-x));
}

// ================= phase device functions =================

__device__ void ph_build_l1(int bid, int t,
        const float* __restrict__ feat, const float* __restrict__ coords,
        const float* __restrict__ W1, const float* __restrict__ b1,
        u32* __restrict__ gcount, u16* __restrict__ pcell,
        float* __restrict__ stats1, float* redsm) {
    if (bid < 128) {
        int n = bid * 256 + t;
        float x = coords[n*3], y = coords[n*3+1], z = coords[n*3+2];
        int cx = min(G-1, max(0, (int)floorf((x + 1.0f) * 3.0f)));
        int cy = min(G-1, max(0, (int)floorf((y + 1.0f) * 3.0f)));
        int cz = min(G-1, max(0, (int)floorf((z + 1.0f) * 3.0f)));
        int gcid = (n >> 13) * NCELL + (cz*G + cy)*G + cx;
        pcell[n] = (u16)gcid;
        atomicAdd(&gcount[gcid], 1u);
    }
    int c = t & 63, w = t >> 6;
    float w1c[C_IN];
    #pragma unroll
    for (int k = 0; k < C_IN; ++k) w1c[k] = W1[k*H_DIM + c];
    float bias = b1[c];
    float s1 = 0.f, s2 = 0.f;
    #pragma unroll 1
    for (int n = bid*4 + w; n < N_PTS; n += 4*NBLK) {
        const float* f = feat + n*C_IN;
        float h = bias;
        #pragma unroll
        for (int k = 0; k < C_IN; ++k) h = fmaf(f[k], w1c[k], h);
        s1 += h; s2 = fmaf(h, h, s2);
    }
    redsm[w*64 + c] = s1;
    redsm[256 + w*64 + c] = s2;
    __syncthreads();
    if (t < 64) {
        float a = redsm[t] + redsm[64+t] + redsm[128+t] + redsm[192+t];
        float b = redsm[256+t] + redsm[320+t] + redsm[384+t] + redsm[448+t];
        atomicAdd(&stats1[t], a);
        atomicAdd(&stats1[64+t], b);
    }
}

__device__ void ph_scan(int bid, int t, const u32* __restrict__ gcount,
        u32* __restrict__ cellstart, u32* __restrict__ cellptr, u32* sc) {
    if (bid != 0) return;
    u32 loc[4]; u32 s = 0;
    #pragma unroll
    for (int j = 0; j < 4; ++j) {
        int idx = t*4 + j;
        loc[j] = (idx < NCELL_T) ? gcount[idx] : 0u;
        s += loc[j];
    }
    sc[t] = s;
    __syncthreads();
    for (int off = 1; off < 256; off <<= 1) {
        u32 v = sc[t];
        if (t >= off) v += sc[t-off];
        __syncthreads();
        sc[t] = v;
        __syncthreads();
    }
    u32 run = sc[t] - s;
    #pragma unroll
    for (int j = 0; j < 4; ++j) {
        int idx = t*4 + j;
        if (idx < NCELL_T) { cellstart[idx] = run; cellptr[idx] = run; }
        run += loc[j];
    }
    if (t == 255) cellstart[NCELL_T] = sc[255];
}

__device__ void ph_scatter_l2(int bid, int t,
        const float* __restrict__ feat, const float* __restrict__ coords,
        const float* __restrict__ W1, const float* __restrict__ b1,
        const float* __restrict__ stats1, const float* __restrict__ g1,
        const float* __restrict__ be1, const float* __restrict__ W2,
        const float* __restrict__ b2, const u16* __restrict__ pcell,
        u32* __restrict__ cellptr, float4* __restrict__ P4s,
        u16* __restrict__ meta16, float* __restrict__ stats2, float* redsm) {
    if (bid < 128) {
        int n = bid * 256 + t;
        float x = coords[n*3], y = coords[n*3+1], z = coords[n*3+2];
        float sq = fmaf(x, x, fmaf(y, y, z*z));
        u32 pos = atomicAdd(&cellptr[pcell[n]], 1u);
        P4s[pos] = make_float4(x, y, z, sq);
        meta16[pos] = (u16)(n & (M_PTS-1));
    }
    int c = t & 63, w = t >> 6;
    float w2c[H_DIM];
    #pragma unroll
    for (int k = 0; k < H_DIM; ++k) w2c[k] = W2[k*H_DIM + c];
    float w1c[C_IN];
    #pragma unroll
    for (int k = 0; k < C_IN; ++k) w1c[k] = W1[k*H_DIM + c];
    float mean1 = stats1[c] * (1.0f/N_PTS);
    float var1  = stats1[64+c] * (1.0f/N_PTS) - mean1*mean1;
    float sc1 = g1[c] * rsqrtf(var1 + 1e-5f);
    float sh1 = be1[c] - mean1*sc1;
    float bias1 = b1[c], bias2 = b2[c];
    float s1 = 0.f, s2 = 0.f;
    #pragma unroll 1
    for (int n = bid*4 + w; n < N_PTS; n += 4*NBLK) {
        const float* f = feat + n*C_IN;
        float h = bias1;
        #pragma unroll
        for (int k = 0; k < C_IN; ++k) h = fmaf(f[k], w1c[k], h);
        float a = gelu_exact(fmaf(sc1, h, sh1));
        float h2 = bias2;
        #pragma unroll
        for (int k = 0; k < H_DIM; ++k) h2 = fmaf(__shfl(a, k, 64), w2c[k], h2);
        s1 += h2; s2 = fmaf(h2, h2, s2);
    }
    __syncthreads();
    redsm[w*64 + c] = s1;
    redsm[256 + w*64 + c] = s2;
    __syncthreads();
    if (t < 64) {
        float a = redsm[t] + redsm[64+t] + redsm[128+t] + redsm[192+t];
        float b = redsm[256+t] + redsm[320+t] + redsm[384+t] + redsm[448+t];
        atomicAdd(&stats2[t], a);
        atomicAdd(&stats2[64+t], b);
    }
}

__device__ void ph_score(int bid, int t,
        const float* __restrict__ feat,
        const float* __restrict__ W1, const float* __restrict__ b1,
        const float* __restrict__ stats1, const float* __restrict__ g1,
        const float* __restrict__ be1, const float* __restrict__ W2,
        const float* __restrict__ b2, const float* __restrict__ stats2,
        const float* __restrict__ g2v, const float* __restrict__ be2,
        const float* __restrict__ W3, const float* __restrict__ b3,
        float* __restrict__ S) {
    int c = t & 63, w = t >> 6;
    float w2c[H_DIM];
    #pragma unroll
    for (int k = 0; k < H_DIM; ++k) w2c[k] = W2[k*H_DIM + c];
    float w1c[C_IN];
    #pragma unroll
    for (int k = 0; k < C_IN; ++k) w1c[k] = W1[k*H_DIM + c];
    float mean1 = stats1[c] * (1.0f/N_PTS);
    float var1  = stats1[64+c] * (1.0f/N_PTS) - mean1*mean1;
    float sc1 = g1[c] * rsqrtf(var1 + 1e-5f);
    float sh1 = be1[c] - mean1*sc1;
    float mean2 = stats2[c] * (1.0f/N_PTS);
    float var2  = stats2[64+c] * (1.0f/N_PTS) - mean2*mean2;
    float sc2 = g2v[c] * rsqrtf(var2 + 1e-5f);
    float sh2 = be2[c] - mean2*sc2;
    float bias1 = b1[c], bias2 = b2[c], w3 = W3[c], bb = b3[0];
    #pragma unroll 1
    for (int n = bid*4 + w; n < N_PTS; n += 4*NBLK) {
        const float* f = feat + n*C_IN;
        float h = bias1;
        #pragma unroll
        for (int k = 0; k < C_IN; ++k) h = fmaf(f[k], w1c[k], h);
        float a = gelu_exact(fmaf(sc1, h, sh1));
        float h2 = bias2;
        #pragma unroll
        for (int k = 0; k < H_DIM; ++k) h2 = fmaf(__shfl(a, k, 64), w2c[k], h2);
        float a2 = gelu_exact(fmaf(sc2, h2, sh2));
        float v = a2 * w3;
        #pragma unroll
        for (int m = 32; m; m >>= 1) v += __shfl_xor(v, m, 64);
        if (c == 0) S[n] = sigmoidf_(v + bb);
    }
}

__device__ void ph_knn(int t,
        const float4* __restrict__ P4s, const u16* __restrict__ meta16,
        const u32* __restrict__ cellstart, const float* __restrict__ S,
        u32* __restrict__ cellq, double* __restrict__ accum,
        u64* buf, int* runsb_s, int* runse_s, int* curcell_s, double* lredsm) {
    int w = t >> 6, lane = t & 63;
    u64 lmask = (1ull << lane) - 1ull;
    double anum=0.0, aden=0.0, aslp=0.0, asln=0.0, asmo=0.0;

    for (;;) {
        __syncthreads();
        if (t == 0) *curcell_s = (int)atomicAdd(cellq, 1u);
        __syncthreads();
        int cell = *curcell_s;
        if (cell >= NCELL_T) break;

        int scene = cell / NCELL;
        int cid = cell - scene*NCELL;
        int cx = cid % G, cy = (cid / G) % G, cz = cid / (G*G);
        int sbase = scene * M_PTS;

        int ccrd[3] = {cx, cy, cz};
        bool wall[3]; int Wn = 0;
        #pragma unroll
        for (int d = 0; d < 3; ++d) { wall[d] = (ccrd[d] == 0 || ccrd[d] == G-1); Wn += wall[d]; }
        int lo[3], hi[3];
        #pragma unroll
        for (int d = 0; d < 3; ++d) {
            if (Wn >= 2 && !wall[d]) { lo[d] = min(max(ccrd[d]-2, 0), G-5); hi[d] = lo[d]+4; }
            else                     { lo[d] = min(max(ccrd[d]-1, 0), G-3); hi[d] = lo[d]+2; }
        }
        float lof[3], hif[3]; bool lw[3], hw[3];
        #pragma unroll
        for (int d = 0; d < 3; ++d) {
            lof[d] = -1.0f + lo[d]*CW; hif[d] = -1.0f + (hi[d]+1)*CW;
            lw[d] = (lo[d] == 0); hw[d] = (hi[d] == G-1);
        }
        int nx = hi[0]-lo[0]+1, ny = hi[1]-lo[1]+1, nz = hi[2]-lo[2]+1;
        int nruns = ny*nz;
        if (t < nruns) {
            int yy = t % ny, zz = t / ny;
            int bc = scene*NCELL + ((lo[2]+zz)*G + (lo[1]+yy))*G + lo[0];
            runsb_s[t] = (int)cellstart[bc];
            runse_s[t] = (int)cellstart[bc + nx];
        }
        int gcid = scene*NCELL + cid;
        int qstart = (int)cellstart[gcid];
        int qn = (int)cellstart[gcid+1] - qstart;
        __syncthreads();

        for (int pq = w; pq < qn; pq += 4) {
            int qglob = qstart + pq;
            float4 qc = P4s[qglob];
            float qsq = qc.w;
            float qd[3] = {qc.x, qc.y, qc.z};
            float cov = 1e9f;
            #pragma unroll
            for (int d = 0; d < 3; ++d) {
                if (!lw[d]) cov = fminf(cov, qd[d] - lof[d]);
                if (!hw[d]) cov = fminf(cov, hif[d] - qd[d]);
            }
            float g2 = cov*cov;
            float axx = fminf(qc.x+1.f, 1.f-qc.x);
            float ayy = fminf(qc.y+1.f, 1.f-qc.y);
            float azz = fminf(qc.z+1.f, 1.f-qc.z);
            float r = 0.2298f;
            #pragma unroll
            for (int it = 0; it < 3; ++it) {
                float ir = 1.0f / r;
                float ux = fminf(axx*ir, 1.f), uy = fminf(ayy*ir, 1.f), uz = fminf(azz*ir, 1.f);
                float fx = 0.25f*(2.f + 3.f*ux - ux*ux*ux);
                float fy = 0.25f*(2.f + 3.f*uy - uy*uy*uy);
                float fz = 0.25f*(2.f + 3.f*uz - uz*uz*uz);
                r = cbrtf(KTGT / (4289.32f * fx * fy * fz));
            }
            float taup = fminf(r*r, g2) - qsq;

            // ---- collect stream (lane-parallel, coalesced) ----
            u32 base = 0;
            for (int rr = 0; rr < nruns; ++rr) {
                int ve = runse_s[rr];
                for (int v0 = runsb_s[rr]; v0 < ve; v0 += 64) {
                    int v = v0 + lane;
                    bool pred = false; u64 key = 0;
                    if (v < ve) {
                        float4 pp = P4s[v];
                        float dot = fmaf(qc.x, pp.x, fmaf(qc.y, pp.y, qc.z*pp.z));
                        float e2 = fmaf(-2.0f, dot, pp.w);
                        if (e2 < taup) {
                            pred = true;
                            float d2 = fmaxf(e2 + qsq, 0.0f);
                            key = ((u64)__float_as_uint(d2) << 32)
                                | ((u64)meta16[v] << 13) | (u64)(u32)(v - sbase);
                        }
                    }
                    u64 mask = __ballot(pred);
                    if (pred) {
                        u32 pos = base + (u32)__popcll(mask & lmask);
                        if (pos < CAP) buf[w*CAP + pos] = key;
                    }
                    base += (u32)__popcll(mask);
                }
            }

            // ---- rare fallback: wave-level ladder redo ----
            if (base < 32u || base > (u32)CAP) {
                u32 n0=0,n1=0,n2=0,n3=0,n4=0,n5=0;
                for (int rr = 0; rr < nruns; ++rr) {
                    int ve = runse_s[rr];
                    for (int v0 = runsb_s[rr]; v0 < ve; v0 += 64) {
                        int v = v0 + lane;
                        if (v < ve) {
                            float4 pp = P4s[v];
                            float dot = fmaf(qc.x, pp.x, fmaf(qc.y, pp.y, qc.z*pp.z));
                            float e2 = fmaf(-2.0f, dot, pp.w);
                            n0 += (e2 < TL0-qsq); n1 += (e2 < TL1-qsq); n2 += (e2 < TL2-qsq);
                            n3 += (e2 < TL3-qsq); n4 += (e2 < TL4-qsq); n5 += (e2 < TL5-qsq);
                        }
                    }
                }
                #pragma unroll
                for (int m = 32; m; m >>= 1) {
                    n0 += __shfl_xor(n0, m, 64); n1 += __shfl_xor(n1, m, 64);
                    n2 += __shfl_xor(n2, m, 64); n3 += __shfl_xor(n3, m, 64);
                    n4 += __shfl_xor(n4, m, 64); n5 += __shfl_xor(n5, m, 64);
                }
                float tau = TL2;
                if (TL3 <= g2) tau = TL3;
                if (TL4 <= g2) tau = TL4;
                if (TL5 <= g2) tau = TL5;
                if      (n0 >= 32u) tau = TL0;
                else if (n1 >= 32u) tau = TL1;
                else if (n2 >= 32u) tau = TL2;
                else if (TL3 <= g2 && n3 >= 32u) tau = TL3;
                else if (TL4 <= g2 && n4 >= 32u) tau = TL4;
                else if (TL5 <= g2 && n5 >= 32u) tau = TL5;
                taup = tau - qsq;
                base = 0;
                for (int rr = 0; rr < nruns; ++rr) {
                    int ve = runse_s[rr];
                    for (int v0 = runsb_s[rr]; v0 < ve; v0 += 64) {
                        int v = v0 + lane;
                        bool pred = false; u64 key = 0;
                        if (v < ve) {
                            float4 pp = P4s[v];
                            float dot = fmaf(qc.x, pp.x, fmaf(qc.y, pp.y, qc.z*pp.z));
                            float e2 = fmaf(-2.0f, dot, pp.w);
                            if (e2 < taup) {
                                pred = true;
                                float d2 = fmaxf(e2 + qsq, 0.0f);
                                key = ((u64)__float_as_uint(d2) << 32)
                                    | ((u64)meta16[v] << 13) | (u64)(u32)(v - sbase);
                            }
                        }
                        u64 mask = __ballot(pred);
                        if (pred) {
                            u32 pos = base + (u32)__popcll(mask & lmask);
                            if (pos < CAP) buf[w*CAP + pos] = key;
                        }
                        base += (u32)__popcll(mask);
                    }
                }
            }

            // ---- rank + losses (lane-parallel over candidates) ----
            u32 Mq = min(base, (u32)CAP);
            float si = S[sbase + (int)meta16[qglob]];
            float smsum = 0.f;
            for (int i = lane; i < (int)Mq; i += 64) {
                u64 mykey = buf[w*CAP + i];
                u32 rank = 0;
                for (u32 j = 0; j < Mq; ++j) rank += (buf[w*CAP + j] < mykey);
                if (rank < 32u) {
                    u32 jl = (u32)(mykey & 0x1FFFu);
                    u32 jo = (u32)((mykey >> 13) & 0x1FFFu);
                    float sj = S[sbase + (int)jo];
                    float sd = fabsf(si - sj);
                    float sim = 1.0f - sd;
                    if (rank < 16u) {
                        float4 cj = P4s[sbase + (int)jl];
                        float dx = qc.x-cj.x, dy = qc.y-cj.y, dz = qc.z-cj.z;
                        float d2 = fmaf(dx,dx,fmaf(dy,dy,dz*dz));
                        float d = sqrtf(fmaxf(d2, 1e-24f));
                        float wgt = expf(-10.0f*d);
                        anum += (double)(wgt*sd*sd);
                        aden += (double)wgt;
                        aslp += (double)logf(sigmoidf_(2.0f*sim) + 1e-8f);
                        if (rank < 8u) smsum += sj;
                    } else {
                        asln += (double)logf(sigmoidf_(-2.0f*sim) + 1e-8f);
                    }
                }
            }
            #pragma unroll
            for (int m = 32; m; m >>= 1) smsum += __shfl_xor(smsum, m, 64);
            if (lane == 0) {
                float dd = si - smsum*0.125f;
                asmo += (double)(dd*dd);
            }
        }
    }

    double v[5] = {anum, aden, aslp, asln, asmo};
    #pragma unroll
    for (int k = 0; k < 5; ++k) {
        for (int m = 32; m; m >>= 1) v[k] += __shfl_xor(v[k], m, 64);
    }
    if ((t & 63) == 0) {
        #pragma unroll
        for (int k = 0; k < 5; ++k) lredsm[w*5 + k] = v[k];
    }
    __syncthreads();
    if (t == 0) {
        #pragma unroll
        for (int k = 0; k < 5; ++k)
            atomicAdd(&accum[k], lredsm[k] + lredsm[5+k] + lredsm[10+k] + lredsm[15+k]);
    }
}

__device__ void ph_final(int bid, int t, const double* __restrict__ accum,
                         float* __restrict__ out) {
    if (bid == 0 && t == 0) {
        double num = accum[0], den = accum[1], slp = accum[2],
               sln = accum[3], ssm = accum[4];
        double loss_loc = num / fmax(den, 1e-8);
        double inv = 1.0 / ((double)N_PTS * 16.0);
        double loss_con = -(slp * inv) - (sln * inv);
        double loss_sm = ssm / (double)N_PTS;
        out[0] = (float)(loss_loc + 0.5*loss_con + 0.2*loss_sm);
    }
}

// ================= mega (cooperative) =================
__global__ __launch_bounds__(256, 2) void mega(
        const float* __restrict__ feat, const float* __restrict__ coords,
        const float* __restrict__ W1, const float* __restrict__ b1,
        const float* __restrict__ g1, const float* __restrict__ be1,
        const float* __restrict__ W2, const float* __restrict__ b2,
        const float* __restrict__ g2v, const float* __restrict__ be2,
        const float* __restrict__ W3, const float* __restrict__ b3,
        char* __restrict__ ws, float* __restrict__ out) {
    cg::grid_group grid = cg::this_grid();
    __shared__ float redsm[512];
    __shared__ u64 buf[4*CAP];
    __shared__ int runsb_s[16], runse_s[16], curcell_s;
    __shared__ double lredsm[20];

    float* stats1   = (float*)(ws);
    float* stats2   = (float*)(ws + 512);
    u32* gcount     = (u32*)(ws + 1024);
    double* accum   = (double*)(ws + 4480);
    u32* cellq      = (u32*)(ws + 4520);
    u32* cellstart  = (u32*)(ws + 4544);
    u32* cellptr    = (u32*)(ws + 8008);
    float* S        = (float*)(ws + 11472);
    float4* P4s     = (float4*)(ws + 142544);
    u16* meta16     = (u16*)(ws + 666832);
    u16* pcell      = (u16*)(ws + 732368);

    int t = threadIdx.x, bid = blockIdx.x;

    ph_build_l1(bid, t, feat, coords, W1, b1, gcount, pcell, stats1, redsm);
    grid.sync();
    ph_scan(bid, t, gcount, cellstart, cellptr, (u32*)redsm);
    grid.sync();
    ph_scatter_l2(bid, t, feat, coords, W1, b1, stats1, g1, be1, W2, b2,
                  pcell, cellptr, P4s, meta16, stats2, redsm);
    grid.sync();
    ph_score(bid, t, feat, W1, b1, stats1, g1, be1, W2, b2, stats2, g2v, be2,
             W3, b3, S);
    grid.sync();
    ph_knn(t, P4s, meta16, cellstart, S, cellq, accum,
           buf, runsb_s, runse_s, &curcell_s, lredsm);
    grid.sync();
    ph_final(bid, t, accum, out);
}

// ================= split fallback kernels =================
__global__ __launch_bounds__(256, 2) void k_phA(const float* feat, const float* coords,
        const float* W1, const float* b1, u32* gcount, u16* pcell, float* stats1) {
    __shared__ float redsm[512];
    ph_build_l1(blockIdx.x, threadIdx.x, feat, coords, W1, b1, gcount, pcell, stats1, redsm);
}
__global__ __launch_bounds__(256) void k_phB(const u32* gcount, u32* cellstart, u32* cellptr) {
    __shared__ u32 sc[256];
    ph_scan(blockIdx.x, threadIdx.x, gcount, cellstart, cellptr, sc);
}
__global__ __launch_bounds__(256, 2) void k_phC(const float* feat, const float* coords,
        const float* W1, const float* b1, const float* stats1, const float* g1,
        const float* be1, const float* W2, const float* b2, const u16* pcell,
        u32* cellptr, float4* P4s, u16* meta16, float* stats2) {
    __shared__ float redsm[512];
    ph_scatter_l2(blockIdx.x, threadIdx.x, feat, coords, W1, b1, stats1, g1, be1,
                  W2, b2, pcell, cellptr, P4s, meta16, stats2, redsm);
}
__global__ __launch_bounds__(256, 2) void k_phD(const float* feat,
        const float* W1, const float* b1, const float* stats1, const float* g1,
        const float* be1, const float* W2, const float* b2, const float* stats2,
        const float* g2v, const float* be2, const float* W3, const float* b3,
        float* S) {
    ph_score(blockIdx.x, threadIdx.x, feat, W1, b1, stats1, g1, be1, W2, b2,
             stats2, g2v, be2, W3, b3, S);
}
__global__ __launch_bounds__(256, 2) void k_phE(const float4* P4s, const u16* meta16,
        const u32* cellstart, const float* S, u32* cellq, double* accum) {
    __shared__ u64 buf[4*CAP];
    __shared__ int runsb_s[16], runse_s[16], curcell_s;
    __shared__ double lredsm[20];
    ph_knn(threadIdx.x, P4s, meta16, cellstart, S, cellq, accum,
           buf, runsb_s, runse_s, &curcell_s, lredsm);
}
__global__ __launch_bounds__(256) void k_phF(const double* accum, float* out) {
    ph_final(blockIdx.x, threadIdx.x, accum, out);
}

extern "C" void kernel_launch(void* const* d_in, const int* in_sizes, int n_in,
                              void* d_out, int out_size, void* d_ws, size_t ws_size,
                              hipStream_t stream) {
    const float* feat   = (const float*)d_in[0];
    const float* coords = (const float*)d_in[1];
    const float* W1 = (const float*)d_in[2];
    const float* b1 = (const float*)d_in[3];
    const float* g1 = (const float*)d_in[4];
    const float* be1= (const float*)d_in[5];
    const float* W2 = (const float*)d_in[6];
    const float* b2 = (const float*)d_in[7];
    const float* g2 = (const float*)d_in[8];
    const float* be2= (const float*)d_in[9];
    const float* W3 = (const float*)d_in[10];
    const float* b3 = (const float*)d_in[11];
    char* ws = (char*)d_ws;
    float* out = (float*)d_out;

    float* stats1   = (float*)(ws);
    float* stats2   = (float*)(ws + 512);
    u32* gcount     = (u32*)(ws + 1024);
    double* accum   = (double*)(ws + 4480);
    u32* cellq      = (u32*)(ws + 4520);
    u32* cellstart  = (u32*)(ws + 4544);
    u32* cellptr    = (u32*)(ws + 8008);
    float* S        = (float*)(ws + 11472);
    float4* P4s     = (float4*)(ws + 142544);
    u16* meta16     = (u16*)(ws + 666832);
    u16* pcell      = (u16*)(ws + 732368);

    hipMemsetAsync(d_ws, 0, 4544, stream);

    void* args[] = {(void*)&feat, (void*)&coords, (void*)&W1, (void*)&b1,
                    (void*)&g1, (void*)&be1, (void*)&W2, (void*)&b2,
                    (void*)&g2, (void*)&be2, (void*)&W3, (void*)&b3,
                    (void*)&ws, (void*)&out};
    hipError_t err = hipLaunchCooperativeKernel((const void*)mega, dim3(NBLK),
                                                dim3(256), args, 0, stream);
    if (err != hipSuccess) {
        // split fallback — identical phases, kernel boundaries as barriers
        hipLaunchKernelGGL(k_phA, dim3(NBLK), dim3(256), 0, stream,
                           feat, coords, W1, b1, gcount, pcell, stats1);
        hipLaunchKernelGGL(k_phB, dim3(1), dim3(256), 0, stream,
                           gcount, cellstart, cellptr);
        hipLaunchKernelGGL(k_phC, dim3(NBLK), dim3(256), 0, stream,
                           feat, coords, W1, b1, stats1, g1, be1, W2, b2,
                           pcell, cellptr, P4s, meta16, stats2);
        hipLaunchKernelGGL(k_phD, dim3(NBLK), dim3(256), 0, stream,
                           feat, W1, b1, stats1, g1, be1, W2, b2, stats2,
                           g2, be2, W3, b3, S);
        hipLaunchKernelGGL(k_phE, dim3(NBLK), dim3(256), 0, stream,
                           P4s, meta16, cellstart, S, cellq, accum);
        hipLaunchKernelGGL(k_phF, dim3(1), dim3(256), 0, stream, accum, out);
    }
}

// Round 6
// 400.982 us; speedup vs baseline: 1.8846x; 1.8846x over previous
//
#include <hip/hip_runtime.h>

typedef unsigned long long u64;
typedef unsigned int u32;
typedef unsigned short u16;

#define N_PTS 32768
#define M_PTS 8192
#define C_IN 6
#define H_DIM 64

#define G 6
#define NCELL 216
#define NCELL_T 864
#define CW (1.0f/3.0f)

#define NBLK 256
#define QPP 64
#define CAPQ 72
#define CAPS 73
#define KTGT 52.0f

#define TL0 0.0494f
#define TL1 0.0740f
#define TL2 0.1110f
#define TL3 0.1736f
#define TL4 0.2600f
#define TL5 0.4000f

// ws layout (bytes):
// 0      : stats1[128]f      (zeroed)
// 512    : stats2[128]f      (zeroed)
// 1024   : gcount[864]u32    (zeroed)  -> 4480
// 4480   : accum[5]double    (zeroed)  -> 4520
// 4520   : donecnt u32       (zeroed)  -> 4524 (memset 0..4544)
// 4544   : cellstart[865]u32 -> 8004 pad 8008
// 8008   : cellptr[864]u32   -> 11464 pad 11472
// 11472  : S[32768]f         -> 142544
// 142544 : P4s[32768]float4  -> 666832
// 666832 : meta16[32768]u16  -> 732368
// 732368 : pcell[32768]u16   -> 797904

__device__ __forceinline__ float gelu_exact(float x) {
    return 0.5f * x * (1.0f + erff(x * 0.70710678118654752f));
}
__device__ __forceinline__ float sigmoidf_(float x) {
    return 1.0f / (1.0f + expf(-x));
}
__device__ __forceinline__ int vsearch(const int* runpre, int nruns, int v) {
    int lo = 0, hi = nruns - 1;
    while (lo < hi) { int mid = (lo + hi + 1) >> 1; if (runpre[mid] <= v) lo = mid; else hi = mid - 1; }
    return lo;
}

// ================= kA: cellpack + layer1 stats =================
__global__ __launch_bounds__(256) void kA(const float* __restrict__ feat,
        const float* __restrict__ coords, const float* __restrict__ W1,
        const float* __restrict__ b1, u32* __restrict__ gcount,
        u16* __restrict__ pcell, float* __restrict__ stats1) {
    __shared__ float red[512];
    int t = threadIdx.x, bid = blockIdx.x;
    if (bid < 128) {
        int n = bid * 256 + t;
        float x = coords[n*3], y = coords[n*3+1], z = coords[n*3+2];
        int cx = min(G-1, max(0, (int)floorf((x + 1.0f) * 3.0f)));
        int cy = min(G-1, max(0, (int)floorf((y + 1.0f) * 3.0f)));
        int cz = min(G-1, max(0, (int)floorf((z + 1.0f) * 3.0f)));
        int gcid = (n >> 13) * NCELL + (cz*G + cy)*G + cx;
        pcell[n] = (u16)gcid;
        atomicAdd(&gcount[gcid], 1u);
    }
    int c = t & 63, w = t >> 6;
    float w1c[C_IN];
    #pragma unroll
    for (int k = 0; k < C_IN; ++k) w1c[k] = W1[k*H_DIM + c];
    float bias = b1[c];
    float s1 = 0.f, s2 = 0.f;
    #pragma unroll 1
    for (int n = bid*4 + w; n < N_PTS; n += 4*NBLK) {
        const float* f = feat + n*C_IN;
        float h = bias;
        #pragma unroll
        for (int k = 0; k < C_IN; ++k) h = fmaf(f[k], w1c[k], h);
        s1 += h; s2 = fmaf(h, h, s2);
    }
    red[w*64 + c] = s1;
    red[256 + w*64 + c] = s2;
    __syncthreads();
    if (t < 64) {
        float a = red[t] + red[64+t] + red[128+t] + red[192+t];
        float b = red[256+t] + red[320+t] + red[384+t] + red[448+t];
        atomicAdd(&stats1[t], a);
        atomicAdd(&stats1[64+t], b);
    }
}

// ================= kB: scan (block 0) + layer2 stats =================
__global__ __launch_bounds__(256) void kB(const float* __restrict__ feat,
        const float* __restrict__ W1, const float* __restrict__ b1,
        const float* __restrict__ stats1, const float* __restrict__ g1,
        const float* __restrict__ be1, const float* __restrict__ W2,
        const float* __restrict__ b2, const u32* __restrict__ gcount,
        u32* __restrict__ cellstart, u32* __restrict__ cellptr,
        float* __restrict__ stats2) {
    __shared__ float red[512];
    __shared__ u32 sc[256];
    int t = threadIdx.x, bid = blockIdx.x;
    if (bid == 0) {
        u32 loc[4]; u32 s = 0;
        #pragma unroll
        for (int j = 0; j < 4; ++j) {
            int idx = t*4 + j;
            loc[j] = (idx < NCELL_T) ? gcount[idx] : 0u;
            s += loc[j];
        }
        sc[t] = s;
        __syncthreads();
        for (int off = 1; off < 256; off <<= 1) {
            u32 v = sc[t];
            if (t >= off) v += sc[t-off];
            __syncthreads();
            sc[t] = v;
            __syncthreads();
        }
        u32 run = sc[t] - s;
        #pragma unroll
        for (int j = 0; j < 4; ++j) {
            int idx = t*4 + j;
            if (idx < NCELL_T) { cellstart[idx] = run; cellptr[idx] = run; }
            run += loc[j];
        }
        if (t == 255) cellstart[NCELL_T] = sc[255];
        __syncthreads();
    }
    int c = t & 63, w = t >> 6;
    float w2c[H_DIM];
    #pragma unroll
    for (int k = 0; k < H_DIM; ++k) w2c[k] = W2[k*H_DIM + c];
    float w1c[C_IN];
    #pragma unroll
    for (int k = 0; k < C_IN; ++k) w1c[k] = W1[k*H_DIM + c];
    float mean1 = stats1[c] * (1.0f/N_PTS);
    float var1  = stats1[64+c] * (1.0f/N_PTS) - mean1*mean1;
    float sc1 = g1[c] * rsqrtf(var1 + 1e-5f);
    float sh1 = be1[c] - mean1*sc1;
    float bias1 = b1[c], bias2 = b2[c];
    float s1 = 0.f, s2 = 0.f;
    #pragma unroll 1
    for (int n = bid*4 + w; n < N_PTS; n += 4*NBLK) {
        const float* f = feat + n*C_IN;
        float h = bias1;
        #pragma unroll
        for (int k = 0; k < C_IN; ++k) h = fmaf(f[k], w1c[k], h);
        float a = gelu_exact(fmaf(sc1, h, sh1));
        float h2 = bias2;
        #pragma unroll
        for (int k = 0; k < H_DIM; ++k) h2 = fmaf(__shfl(a, k, 64), w2c[k], h2);
        s1 += h2; s2 = fmaf(h2, h2, s2);
    }
    red[w*64 + c] = s1;
    red[256 + w*64 + c] = s2;
    __syncthreads();
    if (t < 64) {
        float a = red[t] + red[64+t] + red[128+t] + red[192+t];
        float b = red[256+t] + red[320+t] + red[384+t] + red[448+t];
        atomicAdd(&stats2[t], a);
        atomicAdd(&stats2[64+t], b);
    }
}

// ================= kC: scatter + score =================
__global__ __launch_bounds__(256) void kC(const float* __restrict__ feat,
        const float* __restrict__ coords,
        const float* __restrict__ W1, const float* __restrict__ b1,
        const float* __restrict__ stats1, const float* __restrict__ g1,
        const float* __restrict__ be1, const float* __restrict__ W2,
        const float* __restrict__ b2, const float* __restrict__ stats2,
        const float* __restrict__ g2v, const float* __restrict__ be2,
        const float* __restrict__ W3, const float* __restrict__ b3,
        const u16* __restrict__ pcell, u32* __restrict__ cellptr,
        float4* __restrict__ P4s, u16* __restrict__ meta16,
        float* __restrict__ S) {
    int t = threadIdx.x, bid = blockIdx.x;
    if (bid < 128) {
        int n = bid * 256 + t;
        float x = coords[n*3], y = coords[n*3+1], z = coords[n*3+2];
        float sq = fmaf(x, x, fmaf(y, y, z*z));
        u32 pos = atomicAdd(&cellptr[pcell[n]], 1u);
        P4s[pos] = make_float4(x, y, z, sq);
        meta16[pos] = (u16)(n & (M_PTS-1));
    }
    int c = t & 63, w = t >> 6;
    float w2c[H_DIM];
    #pragma unroll
    for (int k = 0; k < H_DIM; ++k) w2c[k] = W2[k*H_DIM + c];
    float w1c[C_IN];
    #pragma unroll
    for (int k = 0; k < C_IN; ++k) w1c[k] = W1[k*H_DIM + c];
    float mean1 = stats1[c] * (1.0f/N_PTS);
    float var1  = stats1[64+c] * (1.0f/N_PTS) - mean1*mean1;
    float sc1 = g1[c] * rsqrtf(var1 + 1e-5f);
    float sh1 = be1[c] - mean1*sc1;
    float mean2 = stats2[c] * (1.0f/N_PTS);
    float var2  = stats2[64+c] * (1.0f/N_PTS) - mean2*mean2;
    float sc2 = g2v[c] * rsqrtf(var2 + 1e-5f);
    float sh2 = be2[c] - mean2*sc2;
    float bias1 = b1[c], bias2 = b2[c], w3 = W3[c], bb = b3[0];
    #pragma unroll 1
    for (int n = bid*4 + w; n < N_PTS; n += 4*NBLK) {
        const float* f = feat + n*C_IN;
        float h = bias1;
        #pragma unroll
        for (int k = 0; k < C_IN; ++k) h = fmaf(f[k], w1c[k], h);
        float a = gelu_exact(fmaf(sc1, h, sh1));
        float h2 = bias2;
        #pragma unroll
        for (int k = 0; k < H_DIM; ++k) h2 = fmaf(__shfl(a, k, 64), w2c[k], h2);
        float a2 = gelu_exact(fmaf(sc2, h2, sh2));
        float v = a2 * w3;
        #pragma unroll
        for (int m = 32; m; m >>= 1) v += __shfl_xor(v, m, 64);
        if (c == 0) S[n] = sigmoidf_(v + bb);
    }
}

// ================= kD: KNN + losses + final (block per cell) =================
__global__ __launch_bounds__(256) void kD(const float4* __restrict__ P4s,
        const u16* __restrict__ meta16, const u32* __restrict__ cellstart,
        const float* __restrict__ S, double* __restrict__ accum,
        u32* __restrict__ donecnt, float* __restrict__ out) {
    __shared__ u64 buf[64*CAPS];      // 37376 B
    __shared__ float4 tile[512];      // 8192 B (overlaid as ovbuf in fallback)
    __shared__ u32 tmeta[512];        // 2048 B
    __shared__ u32 ccnt[64];
    __shared__ u32 failf[64];
    __shared__ u32 flist[64];
    __shared__ int runsb[16];
    __shared__ int runpre[17];
    __shared__ int miscsi[2];         // nruns, tot
    __shared__ u32 fln;
    __shared__ u32 cnt6[6];
    __shared__ u32 ovcnt;
    __shared__ float smacc;
    __shared__ double lred[4][5];

    int t = threadIdx.x, bid = blockIdx.x;
    int lane = t & 63, w = t >> 6;
    int scene = bid / NCELL;
    int cid = bid - scene*NCELL;
    int cx = cid % G, cy = (cid / G) % G, cz = cid / (G*G);
    int sbase = scene * M_PTS;

    int ccrd[3] = {cx, cy, cz};
    bool wall[3]; int Wn = 0;
    #pragma unroll
    for (int d = 0; d < 3; ++d) { wall[d] = (ccrd[d] == 0 || ccrd[d] == G-1); Wn += wall[d]; }
    int lo[3], hi[3];
    #pragma unroll
    for (int d = 0; d < 3; ++d) {
        if (Wn >= 2 && !wall[d]) { lo[d] = min(max(ccrd[d]-2, 0), G-5); hi[d] = lo[d]+4; }
        else                     { lo[d] = min(max(ccrd[d]-1, 0), G-3); hi[d] = lo[d]+2; }
    }
    float lof[3], hif[3]; bool lw[3], hw[3];
    #pragma unroll
    for (int d = 0; d < 3; ++d) {
        lof[d] = -1.0f + lo[d]*CW; hif[d] = -1.0f + (hi[d]+1)*CW;
        lw[d] = (lo[d] == 0); hw[d] = (hi[d] == G-1);
    }
    if (t == 0) {
        int nr = 0, tot = 0;
        int nx = hi[0]-lo[0]+1;
        for (int z = lo[2]; z <= hi[2]; ++z)
            for (int y = lo[1]; y <= hi[1]; ++y) {
                int bc = scene*NCELL + (z*G + y)*G + lo[0];
                int s0 = (int)cellstart[bc], e0 = (int)cellstart[bc + nx];
                runsb[nr] = s0; runpre[nr] = tot; tot += e0 - s0; ++nr;
            }
        runpre[nr] = tot;
        miscsi[0] = nr; miscsi[1] = tot;
    }
    int gcid = scene*NCELL + cid;
    int qstart = (int)cellstart[gcid];
    int qn = (int)cellstart[gcid+1] - qstart;
    __syncthreads();
    int nruns = miscsi[0], tot = miscsi[1];

    double anum=0.0, aden=0.0, aslp=0.0, asln=0.0, asmo=0.0;

    for (int p0 = 0; p0 < qn; p0 += QPP) {
        int qpp = min(QPP, qn - p0);
        int q = lane, quarter = w;
        bool qact = q < qpp;
        float4 qc = P4s[qstart + p0 + (qact ? q : qpp-1)];
        float qsq = qc.w;
        float qd[3] = {qc.x, qc.y, qc.z};
        float cov = 1e9f;
        #pragma unroll
        for (int d = 0; d < 3; ++d) {
            if (!lw[d]) cov = fminf(cov, qd[d] - lof[d]);
            if (!hw[d]) cov = fminf(cov, hif[d] - qd[d]);
        }
        float g2 = cov*cov;
        float axx = fminf(qc.x+1.f, 1.f-qc.x);
        float ayy = fminf(qc.y+1.f, 1.f-qc.y);
        float azz = fminf(qc.z+1.f, 1.f-qc.z);
        float r = 0.2298f;
        #pragma unroll
        for (int it = 0; it < 3; ++it) {
            float ir = 1.0f / r;
            float ux = fminf(axx*ir, 1.f), uy = fminf(ayy*ir, 1.f), uz = fminf(azz*ir, 1.f);
            float fx = 0.25f*(2.f + 3.f*ux - ux*ux*ux);
            float fy = 0.25f*(2.f + 3.f*uy - uy*uy*uy);
            float fz = 0.25f*(2.f + 3.f*uz - uz*uz*uz);
            r = cbrtf(KTGT / (4289.32f * fx * fy * fz));
        }
        float taup = qact ? (fminf(r*r, g2) - qsq) : -1e30f;

        if (t < 64) { ccnt[t] = 0; failf[t] = 0; }
        if (t == 0) fln = 0;
        __syncthreads();

        // ---- single collect stream: chunked LDS staging, broadcast reads ----
        for (int cb = 0; cb < tot; cb += 512) {
            int cnum = min(512, tot - cb);
            for (int j = t; j < cnum; j += 256) {
                int rr = vsearch(runpre, nruns, cb + j);
                int p = runsb[rr] + (cb + j - runpre[rr]);
                tile[j] = P4s[p];
                tmeta[j] = ((u32)meta16[p] << 13) | (u32)(p - sbase);
            }
            __syncthreads();
            #pragma unroll 4
            for (int i = quarter; i < cnum; i += 4) {
                float4 pp = tile[i];
                float dot = fmaf(qc.x, pp.x, fmaf(qc.y, pp.y, qc.z*pp.z));
                float e2 = fmaf(-2.0f, dot, pp.w);
                if (e2 < taup) {
                    float d2 = fmaxf(e2 + qsq, 0.0f);
                    u64 key = ((u64)__float_as_uint(d2) << 32) | (u64)tmeta[i];
                    u32 pos = atomicAdd(&ccnt[q], 1u);
                    if (pos < CAPQ) buf[q*CAPS + pos] = key;
                }
            }
            __syncthreads();
        }

        // ---- detect failed queries ----
        if (t < qpp) {
            u32 cc = ccnt[t];
            if (cc < 32u || cc > (u32)CAPQ) {
                failf[t] = 1;
                u32 fp = atomicAdd(&fln, 1u);
                flist[fp] = (u32)t;
            }
        }
        __syncthreads();

        // ---- rare block-cooperative ladder fallback ----
        int nf = (int)fln;
        u64* ovbuf = (u64*)tile;
        for (int f = 0; f < nf; ++f) {
            int fq = (int)flist[f];
            float4 fqc = P4s[qstart + p0 + fq];
            float fsq = fqc.w;
            float fcov = 1e9f;
            float fqd[3] = {fqc.x, fqc.y, fqc.z};
            #pragma unroll
            for (int d = 0; d < 3; ++d) {
                if (!lw[d]) fcov = fminf(fcov, fqd[d] - lof[d]);
                if (!hw[d]) fcov = fminf(fcov, hif[d] - fqd[d]);
            }
            float fg2 = fcov*fcov;
            if (t < 6) cnt6[t] = 0;
            if (t == 0) { ovcnt = 0; smacc = 0.f; }
            __syncthreads();
            u32 c0=0,c1=0,c2=0,c3=0,c4=0,c5=0;
            for (int v = t; v < tot; v += 256) {
                int rr = vsearch(runpre, nruns, v);
                float4 pp = P4s[runsb[rr] + (v - runpre[rr])];
                float dot = fmaf(fqc.x, pp.x, fmaf(fqc.y, pp.y, fqc.z*pp.z));
                float e2 = fmaf(-2.0f, dot, pp.w);
                c0 += (e2 < TL0-fsq); c1 += (e2 < TL1-fsq); c2 += (e2 < TL2-fsq);
                c3 += (e2 < TL3-fsq); c4 += (e2 < TL4-fsq); c5 += (e2 < TL5-fsq);
            }
            #pragma unroll
            for (int m = 32; m; m >>= 1) {
                c0 += __shfl_xor(c0, m, 64); c1 += __shfl_xor(c1, m, 64);
                c2 += __shfl_xor(c2, m, 64); c3 += __shfl_xor(c3, m, 64);
                c4 += __shfl_xor(c4, m, 64); c5 += __shfl_xor(c5, m, 64);
            }
            if (lane == 0) {
                atomicAdd(&cnt6[0], c0); atomicAdd(&cnt6[1], c1);
                atomicAdd(&cnt6[2], c2); atomicAdd(&cnt6[3], c3);
                atomicAdd(&cnt6[4], c4); atomicAdd(&cnt6[5], c5);
            }
            __syncthreads();
            float tau = TL2;
            if (TL3 <= fg2) tau = TL3;
            if (TL4 <= fg2) tau = TL4;
            if (TL5 <= fg2) tau = TL5;
            if      (cnt6[0] >= 32u) tau = TL0;
            else if (cnt6[1] >= 32u) tau = TL1;
            else if (cnt6[2] >= 32u) tau = TL2;
            else if (TL3 <= fg2 && cnt6[3] >= 32u) tau = TL3;
            else if (TL4 <= fg2 && cnt6[4] >= 32u) tau = TL4;
            else if (TL5 <= fg2 && cnt6[5] >= 32u) tau = TL5;
            float ftp = tau - fsq;
            for (int v = t; v < tot; v += 256) {
                int rr = vsearch(runpre, nruns, v);
                int p = runsb[rr] + (v - runpre[rr]);
                float4 pp = P4s[p];
                float dot = fmaf(fqc.x, pp.x, fmaf(fqc.y, pp.y, fqc.z*pp.z));
                float e2 = fmaf(-2.0f, dot, pp.w);
                if (e2 < ftp) {
                    float d2 = fmaxf(e2 + fsq, 0.0f);
                    u64 key = ((u64)__float_as_uint(d2) << 32)
                            | ((u64)meta16[p] << 13) | (u64)(u32)(p - sbase);
                    u32 pos = atomicAdd(&ovcnt, 1u);
                    if (pos < 1024u) ovbuf[pos] = key;
                }
            }
            __syncthreads();
            u32 Mf = min(ovcnt, 1024u);
            float fsi = S[sbase + (int)meta16[qstart + p0 + fq]];
            for (int i = t; i < (int)Mf; i += 256) {
                u64 mykey = ovbuf[i];
                u32 rank = 0;
                for (u32 j = 0; j < Mf; ++j) rank += (ovbuf[j] < mykey);
                if (rank < 32u) {
                    u32 jl = (u32)(mykey & 0x1FFFu);
                    u32 jo = (u32)((mykey >> 13) & 0x1FFFu);
                    float sj = S[sbase + (int)jo];
                    float sd = fabsf(fsi - sj);
                    float sim = 1.0f - sd;
                    if (rank < 16u) {
                        float4 cj = P4s[sbase + (int)jl];
                        float dx = fqc.x-cj.x, dy = fqc.y-cj.y, dz = fqc.z-cj.z;
                        float d2 = fmaf(dx,dx,fmaf(dy,dy,dz*dz));
                        float d = sqrtf(fmaxf(d2, 1e-24f));
                        float wgt = expf(-10.0f*d);
                        anum += (double)(wgt*sd*sd);
                        aden += (double)wgt;
                        aslp += (double)logf(sigmoidf_(2.0f*sim) + 1e-8f);
                        if (rank < 8u) atomicAdd(&smacc, sj);
                    } else {
                        asln += (double)logf(sigmoidf_(-2.0f*sim) + 1e-8f);
                    }
                }
            }
            __syncthreads();
            if (t == 0) {
                float dd = fsi - smacc*0.125f;
                asmo += (double)(dd*dd);
            }
            __syncthreads();
        }

        // ---- rank + losses (4 threads / query, register-chunked) ----
        int tq = t >> 2, l4 = t & 3;
        bool ract = (tq < qpp) && (failf[tq] == 0u);
        u32 Mq = ract ? min(ccnt[tq], (u32)CAPQ) : 0u;
        int qs = qstart + p0 + (ract ? tq : 0);
        float4 qf = P4s[qs];
        float si = S[sbase + (int)meta16[qs]];
        double num=0.0, den=0.0, slp=0.0, sln=0.0;
        float smsum = 0.f;
        u32 perT = (Mq > (u32)l4) ? ((Mq - (u32)l4 + 3u) >> 2) : 0u;
        for (u32 cb2 = 0; cb2 < perT; cb2 += 8) {
            u32 cnt = min(8u, perT - cb2);
            u64 myk[8]; u32 rk[8];
            #pragma unroll
            for (int k = 0; k < 8; ++k) {
                myk[k] = (k < (int)cnt) ? buf[tq*CAPS + l4 + 4*(cb2 + (u32)k)] : ~0ull;
                rk[k] = 0;
            }
            for (u32 j = 0; j < Mq; ++j) {
                u64 kj = buf[tq*CAPS + j];
                #pragma unroll
                for (int k = 0; k < 8; ++k) rk[k] += (kj < myk[k]);
            }
            #pragma unroll
            for (int k = 0; k < 8; ++k) {
                if (k < (int)cnt && rk[k] < 32) {
                    u64 key = myk[k];
                    u32 jl = (u32)(key & 0x1FFFu);
                    u32 jo = (u32)((key >> 13) & 0x1FFFu);
                    float sj = S[sbase + (int)jo];
                    float sd = fabsf(si - sj);
                    float sim = 1.0f - sd;
                    if (rk[k] < 16) {
                        float4 cj = P4s[sbase + (int)jl];
                        float dx = qf.x-cj.x, dy = qf.y-cj.y, dz = qf.z-cj.z;
                        float d2 = fmaf(dx,dx,fmaf(dy,dy,dz*dz));
                        float d = sqrtf(fmaxf(d2, 1e-24f));
                        float wgt = expf(-10.0f*d);
                        num += (double)(wgt*sd*sd);
                        den += (double)wgt;
                        slp += (double)logf(sigmoidf_(2.0f*sim) + 1e-8f);
                        if (rk[k] < 8) smsum += sj;
                    } else {
                        sln += (double)logf(sigmoidf_(-2.0f*sim) + 1e-8f);
                    }
                }
            }
        }
        smsum += __shfl_xor(smsum, 1, 64);
        smsum += __shfl_xor(smsum, 2, 64);
        anum += num; aden += den; aslp += slp; asln += sln;
        if (ract && l4 == 0) {
            float dd = si - smsum*0.125f;
            asmo += (double)(dd*dd);
        }
        __syncthreads();   // buf/ccnt reuse next pass
    }

    // ---- block reduce + global accumulate + fused final ----
    double v[5] = {anum, aden, aslp, asln, asmo};
    #pragma unroll
    for (int k = 0; k < 5; ++k) {
        for (int m = 32; m; m >>= 1) v[k] += __shfl_xor(v[k], m, 64);
    }
    if (lane == 0) {
        #pragma unroll
        for (int k = 0; k < 5; ++k) lred[w][k] = v[k];
    }
    __syncthreads();
    if (t == 0) {
        #pragma unroll
        for (int k = 0; k < 5; ++k)
            atomicAdd(&accum[k], lred[0][k] + lred[1][k] + lred[2][k] + lred[3][k]);
        __threadfence();
        u32 old = atomicAdd(donecnt, 1u);
        if (old == (u32)(NCELL_T - 1)) {
            double a0 = atomicAdd(&accum[0], 0.0);
            double a1 = atomicAdd(&accum[1], 0.0);
            double a2 = atomicAdd(&accum[2], 0.0);
            double a3 = atomicAdd(&accum[3], 0.0);
            double a4 = atomicAdd(&accum[4], 0.0);
            double loss_loc = a0 / fmax(a1, 1e-8);
            double inv = 1.0 / ((double)N_PTS * 16.0);
            double loss_con = -(a2 * inv) - (a3 * inv);
            double loss_sm = a4 / (double)N_PTS;
            out[0] = (float)(loss_loc + 0.5*loss_con + 0.2*loss_sm);
        }
    }
}

extern "C" void kernel_launch(void* const* d_in, const int* in_sizes, int n_in,
                              void* d_out, int out_size, void* d_ws, size_t ws_size,
                              hipStream_t stream) {
    const float* feat   = (const float*)d_in[0];
    const float* coords = (const float*)d_in[1];
    const float* W1 = (const float*)d_in[2];
    const float* b1 = (const float*)d_in[3];
    const float* g1 = (const float*)d_in[4];
    const float* be1= (const float*)d_in[5];
    const float* W2 = (const float*)d_in[6];
    const float* b2 = (const float*)d_in[7];
    const float* g2 = (const float*)d_in[8];
    const float* be2= (const float*)d_in[9];
    const float* W3 = (const float*)d_in[10];
    const float* b3 = (const float*)d_in[11];
    char* ws = (char*)d_ws;

    float* stats1   = (float*)(ws);
    float* stats2   = (float*)(ws + 512);
    u32* gcount     = (u32*)(ws + 1024);
    double* accum   = (double*)(ws + 4480);
    u32* donecnt    = (u32*)(ws + 4520);
    u32* cellstart  = (u32*)(ws + 4544);
    u32* cellptr    = (u32*)(ws + 8008);
    float* S        = (float*)(ws + 11472);
    float4* P4s     = (float4*)(ws + 142544);
    u16* meta16     = (u16*)(ws + 666832);
    u16* pcell      = (u16*)(ws + 732368);

    hipMemsetAsync(d_ws, 0, 4544, stream);

    hipLaunchKernelGGL(kA, dim3(NBLK), dim3(256), 0, stream,
                       feat, coords, W1, b1, gcount, pcell, stats1);
    hipLaunchKernelGGL(kB, dim3(NBLK), dim3(256), 0, stream,
                       feat, W1, b1, stats1, g1, be1, W2, b2,
                       gcount, cellstart, cellptr, stats2);
    hipLaunchKernelGGL(kC, dim3(NBLK), dim3(256), 0, stream,
                       feat, coords, W1, b1, stats1, g1, be1, W2, b2,
                       stats2, g2, be2, W3, b3, pcell, cellptr, P4s, meta16, S);
    hipLaunchKernelGGL(kD, dim3(NCELL_T), dim3(256), 0, stream,
                       P4s, meta16, cellstart, S, accum, donecnt, (float*)d_out);
}

// Round 7
// 346.415 us; speedup vs baseline: 2.1815x; 1.1575x over previous
//
#include <hip/hip_runtime.h>

typedef unsigned long long u64;
typedef unsigned int u32;
typedef unsigned short u16;

#define N_PTS 32768
#define M_PTS 8192
#define C_IN 6
#define H_DIM 64

#define G 6
#define NCELL 216
#define NCELL_T 864
#define CW (1.0f/3.0f)

#define NBLK 256
#define KTGT 48.0f

#define TL0 0.0494f
#define TL1 0.0740f
#define TL2 0.1110f
#define TL3 0.1736f
#define TL4 0.2600f
#define TL5 0.4000f

// ws layout (bytes):
// 0      : stats1[128]f      (zeroed)
// 512    : stats2[128]f      (zeroed)
// 1024   : gcount[864]u32    (zeroed)  -> 4480
// 4480   : accum[5]double    (zeroed)  -> 4520
// 4520   : donecnt u32       (zeroed)  -> 4524 (memset 0..4544)
// 4544   : cellstart[865]u32 -> 8004 pad 8008
// 8008   : cellptr[864]u32   -> 11464 pad 11472
// 11472  : S[32768]f         -> 142544
// 142544 : P4s[32768]float4  -> 666832
// 666832 : meta16[32768]u16  -> 732368
// 732368 : pcell[32768]u16   -> 797904

__device__ __forceinline__ float gelu_exact(float x) {
    return 0.5f * x * (1.0f + erff(x * 0.70710678118654752f));
}
__device__ __forceinline__ float sigmoidf_(float x) {
    return 1.0f / (1.0f + expf(-x));
}
__device__ __forceinline__ u64 u64min_(u64 a, u64 b) { return a < b ? a : b; }
__device__ __forceinline__ u64 u64max_(u64 a, u64 b) { return a < b ? b : a; }

// ascending bitonic sort of 64 u64 keys across the wave's lanes
__device__ __forceinline__ u64 bitonic_sort64(u64 key, int lane) {
    #pragma unroll
    for (int k = 2; k <= 64; k <<= 1) {
        #pragma unroll
        for (int j = k >> 1; j; j >>= 1) {
            u64 pk = __shfl_xor(key, j, 64);
            bool up = ((lane & k) == 0);
            bool tmin = (((lane & j) == 0) == up);
            key = tmin ? u64min_(key, pk) : u64max_(key, pk);
        }
    }
    return key;
}

// ================= kA: cellpack + layer1 stats =================
__global__ __launch_bounds__(256) void kA(const float* __restrict__ feat,
        const float* __restrict__ coords, const float* __restrict__ W1,
        const float* __restrict__ b1, u32* __restrict__ gcount,
        u16* __restrict__ pcell, float* __restrict__ stats1) {
    __shared__ float red[512];
    int t = threadIdx.x, bid = blockIdx.x;
    if (bid < 128) {
        int n = bid * 256 + t;
        float x = coords[n*3], y = coords[n*3+1], z = coords[n*3+2];
        int cx = min(G-1, max(0, (int)floorf((x + 1.0f) * 3.0f)));
        int cy = min(G-1, max(0, (int)floorf((y + 1.0f) * 3.0f)));
        int cz = min(G-1, max(0, (int)floorf((z + 1.0f) * 3.0f)));
        int gcid = (n >> 13) * NCELL + (cz*G + cy)*G + cx;
        pcell[n] = (u16)gcid;
        atomicAdd(&gcount[gcid], 1u);
    }
    int c = t & 63, w = t >> 6;
    float w1c[C_IN];
    #pragma unroll
    for (int k = 0; k < C_IN; ++k) w1c[k] = W1[k*H_DIM + c];
    float bias = b1[c];
    float s1 = 0.f, s2 = 0.f;
    #pragma unroll 1
    for (int n = bid*8 + w*2; n < N_PTS; n += NBLK*8) {
        const float* fa = feat + n*C_IN;
        const float* fb = feat + (n+1)*C_IN;
        float ha = bias, hb = bias;
        #pragma unroll
        for (int k = 0; k < C_IN; ++k) {
            ha = fmaf(fa[k], w1c[k], ha);
            hb = fmaf(fb[k], w1c[k], hb);
        }
        s1 += ha + hb;
        s2 = fmaf(ha, ha, s2); s2 = fmaf(hb, hb, s2);
    }
    red[w*64 + c] = s1;
    red[256 + w*64 + c] = s2;
    __syncthreads();
    if (t < 64) {
        float a = red[t] + red[64+t] + red[128+t] + red[192+t];
        float b = red[256+t] + red[320+t] + red[384+t] + red[448+t];
        atomicAdd(&stats1[t], a);
        atomicAdd(&stats1[64+t], b);
    }
}

// ================= kB: scan (block 0) + layer2 stats =================
__global__ __launch_bounds__(256) void kB(const float* __restrict__ feat,
        const float* __restrict__ W1, const float* __restrict__ b1,
        const float* __restrict__ stats1, const float* __restrict__ g1,
        const float* __restrict__ be1, const float* __restrict__ W2,
        const float* __restrict__ b2, const u32* __restrict__ gcount,
        u32* __restrict__ cellstart, u32* __restrict__ cellptr,
        float* __restrict__ stats2) {
    __shared__ float red[512];
    __shared__ u32 sc[256];
    int t = threadIdx.x, bid = blockIdx.x;
    if (bid == 0) {
        u32 loc[4]; u32 s = 0;
        #pragma unroll
        for (int j = 0; j < 4; ++j) {
            int idx = t*4 + j;
            loc[j] = (idx < NCELL_T) ? gcount[idx] : 0u;
            s += loc[j];
        }
        sc[t] = s;
        __syncthreads();
        for (int off = 1; off < 256; off <<= 1) {
            u32 v = sc[t];
            if (t >= off) v += sc[t-off];
            __syncthreads();
            sc[t] = v;
            __syncthreads();
        }
        u32 run = sc[t] - s;
        #pragma unroll
        for (int j = 0; j < 4; ++j) {
            int idx = t*4 + j;
            if (idx < NCELL_T) { cellstart[idx] = run; cellptr[idx] = run; }
            run += loc[j];
        }
        if (t == 255) cellstart[NCELL_T] = sc[255];
        __syncthreads();
    }
    int c = t & 63, w = t >> 6;
    float w2c[H_DIM];
    #pragma unroll
    for (int k = 0; k < H_DIM; ++k) w2c[k] = W2[k*H_DIM + c];
    float w1c[C_IN];
    #pragma unroll
    for (int k = 0; k < C_IN; ++k) w1c[k] = W1[k*H_DIM + c];
    float mean1 = stats1[c] * (1.0f/N_PTS);
    float var1  = stats1[64+c] * (1.0f/N_PTS) - mean1*mean1;
    float sc1 = g1[c] * rsqrtf(var1 + 1e-5f);
    float sh1 = be1[c] - mean1*sc1;
    float bias1 = b1[c], bias2 = b2[c];
    float s1 = 0.f, s2 = 0.f;
    #pragma unroll 1
    for (int n = bid*8 + w*2; n < N_PTS; n += NBLK*8) {
        const float* fa = feat + n*C_IN;
        const float* fb = feat + (n+1)*C_IN;
        float ha = bias1, hb = bias1;
        #pragma unroll
        for (int k = 0; k < C_IN; ++k) {
            ha = fmaf(fa[k], w1c[k], ha);
            hb = fmaf(fb[k], w1c[k], hb);
        }
        float aa = gelu_exact(fmaf(sc1, ha, sh1));
        float ab = gelu_exact(fmaf(sc1, hb, sh1));
        float h2a = bias2, h2b = bias2;
        #pragma unroll
        for (int k = 0; k < H_DIM; ++k) {
            h2a = fmaf(__shfl(aa, k, 64), w2c[k], h2a);
            h2b = fmaf(__shfl(ab, k, 64), w2c[k], h2b);
        }
        s1 += h2a + h2b;
        s2 = fmaf(h2a, h2a, s2); s2 = fmaf(h2b, h2b, s2);
    }
    red[w*64 + c] = s1;
    red[256 + w*64 + c] = s2;
    __syncthreads();
    if (t < 64) {
        float a = red[t] + red[64+t] + red[128+t] + red[192+t];
        float b = red[256+t] + red[320+t] + red[384+t] + red[448+t];
        atomicAdd(&stats2[t], a);
        atomicAdd(&stats2[64+t], b);
    }
}

// ================= kC: scatter + score =================
__global__ __launch_bounds__(256) void kC(const float* __restrict__ feat,
        const float* __restrict__ coords,
        const float* __restrict__ W1, const float* __restrict__ b1,
        const float* __restrict__ stats1, const float* __restrict__ g1,
        const float* __restrict__ be1, const float* __restrict__ W2,
        const float* __restrict__ b2, const float* __restrict__ stats2,
        const float* __restrict__ g2v, const float* __restrict__ be2,
        const float* __restrict__ W3, const float* __restrict__ b3,
        const u16* __restrict__ pcell, u32* __restrict__ cellptr,
        float4* __restrict__ P4s, u16* __restrict__ meta16,
        float* __restrict__ S) {
    int t = threadIdx.x, bid = blockIdx.x;
    if (bid < 128) {
        int n = bid * 256 + t;
        float x = coords[n*3], y = coords[n*3+1], z = coords[n*3+2];
        float sq = fmaf(x, x, fmaf(y, y, z*z));
        u32 pos = atomicAdd(&cellptr[pcell[n]], 1u);
        P4s[pos] = make_float4(x, y, z, sq);
        meta16[pos] = (u16)(n & (M_PTS-1));
    }
    int c = t & 63, w = t >> 6;
    float w2c[H_DIM];
    #pragma unroll
    for (int k = 0; k < H_DIM; ++k) w2c[k] = W2[k*H_DIM + c];
    float w1c[C_IN];
    #pragma unroll
    for (int k = 0; k < C_IN; ++k) w1c[k] = W1[k*H_DIM + c];
    float mean1 = stats1[c] * (1.0f/N_PTS);
    float var1  = stats1[64+c] * (1.0f/N_PTS) - mean1*mean1;
    float sc1 = g1[c] * rsqrtf(var1 + 1e-5f);
    float sh1 = be1[c] - mean1*sc1;
    float mean2 = stats2[c] * (1.0f/N_PTS);
    float var2  = stats2[64+c] * (1.0f/N_PTS) - mean2*mean2;
    float sc2 = g2v[c] * rsqrtf(var2 + 1e-5f);
    float sh2 = be2[c] - mean2*sc2;
    float bias1 = b1[c], bias2 = b2[c], w3 = W3[c], bb = b3[0];
    #pragma unroll 1
    for (int n = bid*8 + w*2; n < N_PTS; n += NBLK*8) {
        const float* fa = feat + n*C_IN;
        const float* fb = feat + (n+1)*C_IN;
        float ha = bias1, hb = bias1;
        #pragma unroll
        for (int k = 0; k < C_IN; ++k) {
            ha = fmaf(fa[k], w1c[k], ha);
            hb = fmaf(fb[k], w1c[k], hb);
        }
        float aa = gelu_exact(fmaf(sc1, ha, sh1));
        float ab = gelu_exact(fmaf(sc1, hb, sh1));
        float h2a = bias2, h2b = bias2;
        #pragma unroll
        for (int k = 0; k < H_DIM; ++k) {
            h2a = fmaf(__shfl(aa, k, 64), w2c[k], h2a);
            h2b = fmaf(__shfl(ab, k, 64), w2c[k], h2b);
        }
        float a2a = gelu_exact(fmaf(sc2, h2a, sh2));
        float a2b = gelu_exact(fmaf(sc2, h2b, sh2));
        float va = a2a * w3, vb = a2b * w3;
        #pragma unroll
        for (int m = 32; m; m >>= 1) {
            va += __shfl_xor(va, m, 64);
            vb += __shfl_xor(vb, m, 64);
        }
        if (c == 0) {
            S[n] = sigmoidf_(va + bb);
            S[n+1] = sigmoidf_(vb + bb);
        }
    }
}

// ================= kD: KNN + losses + final (block/cell, wave/query) =======
__global__ __launch_bounds__(256) void kD(const float4* __restrict__ P4s,
        const u16* __restrict__ meta16, const u32* __restrict__ cellstart,
        const float* __restrict__ S, double* __restrict__ accum,
        u32* __restrict__ donecnt, float* __restrict__ out) {
    __shared__ u64 wavebuf[4][128];     // 4 KB; overlaid as ovbuf in fallback
    __shared__ int runsb[16], runse[16];
    __shared__ int nruns_s;
    __shared__ u32 flistB[64];
    __shared__ u32 flnB;
    __shared__ u32 cnt6[6];
    __shared__ u32 ovcnt;
    __shared__ float smacc;
    __shared__ double lred[4][5];

    int t = threadIdx.x, bid = blockIdx.x;
    int lane = t & 63, w = t >> 6;
    u64 lmask = (1ull << lane) - 1ull;
    int scene = bid / NCELL;
    int cid = bid - scene*NCELL;
    int cx = cid % G, cy = (cid / G) % G, cz = cid / (G*G);
    int sbase = scene * M_PTS;

    int ccrd[3] = {cx, cy, cz};
    bool wall[3]; int Wn = 0;
    #pragma unroll
    for (int d = 0; d < 3; ++d) { wall[d] = (ccrd[d] == 0 || ccrd[d] == G-1); Wn += wall[d]; }
    int lo[3], hi[3];
    #pragma unroll
    for (int d = 0; d < 3; ++d) {
        if (Wn >= 2 && !wall[d]) { lo[d] = min(max(ccrd[d]-2, 0), G-5); hi[d] = lo[d]+4; }
        else                     { lo[d] = min(max(ccrd[d]-1, 0), G-3); hi[d] = lo[d]+2; }
    }
    float lof[3], hif[3]; bool lw[3], hw[3];
    #pragma unroll
    for (int d = 0; d < 3; ++d) {
        lof[d] = -1.0f + lo[d]*CW; hif[d] = -1.0f + (hi[d]+1)*CW;
        lw[d] = (lo[d] == 0); hw[d] = (hi[d] == G-1);
    }
    if (t == 0) {
        int nr = 0;
        int nx = hi[0]-lo[0]+1;
        for (int z = lo[2]; z <= hi[2]; ++z)
            for (int y = lo[1]; y <= hi[1]; ++y) {
                int bc = scene*NCELL + (z*G + y)*G + lo[0];
                runsb[nr] = (int)cellstart[bc];
                runse[nr] = (int)cellstart[bc + nx];
                ++nr;
            }
        nruns_s = nr;
        flnB = 0;
    }
    int gcid = scene*NCELL + cid;
    int qstart = (int)cellstart[gcid];
    int qn = (int)cellstart[gcid+1] - qstart;
    __syncthreads();
    int nruns = nruns_s;

    double anum=0.0, aden=0.0, aslp=0.0, asln=0.0, asmo=0.0;

    // ---- main: wave per query, no block barriers ----
    for (int pq = w; pq < qn; pq += 4) {
        int qglob = qstart + pq;
        float4 qc = P4s[qglob];
        float qsq = qc.w;
        float qd[3] = {qc.x, qc.y, qc.z};
        float cov = 1e9f;
        #pragma unroll
        for (int d = 0; d < 3; ++d) {
            if (!lw[d]) cov = fminf(cov, qd[d] - lof[d]);
            if (!hw[d]) cov = fminf(cov, hif[d] - qd[d]);
        }
        float g2 = cov*cov;
        float axx = fminf(qc.x+1.f, 1.f-qc.x);
        float ayy = fminf(qc.y+1.f, 1.f-qc.y);
        float azz = fminf(qc.z+1.f, 1.f-qc.z);
        float r = 0.224f;
        #pragma unroll
        for (int it = 0; it < 3; ++it) {
            float ir = 1.0f / r;
            float ux = fminf(axx*ir, 1.f), uy = fminf(ayy*ir, 1.f), uz = fminf(azz*ir, 1.f);
            float fx = 0.25f*(2.f + 3.f*ux - ux*ux*ux);
            float fy = 0.25f*(2.f + 3.f*uy - uy*uy*uy);
            float fz = 0.25f*(2.f + 3.f*uz - uz*uz*uz);
            r = cbrtf(KTGT / (4289.32f * fx * fy * fz));
        }
        float taup = fminf(r*r, g2) - qsq;

        // coalesced global scan; ballot-compaction into per-wave LDS strip
        u32 base = 0;
        for (int rr = 0; rr < nruns; ++rr) {
            int ve = runse[rr];
            #pragma unroll 1
            for (int v0 = runsb[rr]; v0 < ve; v0 += 64) {
                int v = v0 + lane;
                bool pred = false; u64 key = 0;
                if (v < ve) {
                    float4 pp = P4s[v];
                    float dot = fmaf(qc.x, pp.x, fmaf(qc.y, pp.y, qc.z*pp.z));
                    float e2 = fmaf(-2.0f, dot, pp.w);
                    if (e2 < taup) {
                        pred = true;
                        float d2 = fmaxf(e2 + qsq, 0.0f);
                        key = ((u64)__float_as_uint(d2) << 13) | (u64)meta16[v];
                    }
                }
                u64 mask = __ballot(pred);
                if (pred) {
                    u32 pos = base + (u32)__popcll(mask & lmask);
                    if (pos < 128u) wavebuf[w][pos] = key;
                }
                base += (u32)__popcll(mask);
            }
        }

        if (base < 32u || base > 128u) {
            if (lane == 0) {
                u32 idx = atomicAdd(&flnB, 1u);
                if (idx < 64u) flistB[idx] = (u32)qglob;
            }
            continue;
        }

        // sort: top-32 exact (keys carry d2 + orig-idx tie-break)
        u32 M = base;
        u64 k0 = (lane < (int)min(M, 64u)) ? wavebuf[w][lane] : ~0ull;
        k0 = bitonic_sort64(k0, lane);
        if (M > 64u) {
            u64 k1 = (lane < (int)(M - 64u)) ? wavebuf[w][64 + lane] : ~0ull;
            k1 = bitonic_sort64(k1, lane);
            u64 pk = __shfl(k1, 63 - lane, 64);
            u64 lo2 = u64min_(k0, pk);
            #pragma unroll
            for (int j = 32; j; j >>= 1) {
                u64 pj = __shfl_xor(lo2, j, 64);
                lo2 = ((lane & j) == 0) ? u64min_(lo2, pj) : u64max_(lo2, pj);
            }
            k0 = lo2;
        }

        // eval: lane i holds i-th nearest
        float si = S[sbase + (int)meta16[qglob]];
        float smsum = 0.f;
        if (lane < 32) {
            float d2 = __uint_as_float((u32)(k0 >> 13));
            u32 jo = (u32)(k0 & 0x1FFFu);
            float sj = S[sbase + (int)jo];
            float sd = fabsf(si - sj);
            float sim = 1.0f - sd;
            if (lane < 16) {
                float d = sqrtf(fmaxf(d2, 1e-24f));
                float wgt = expf(-10.0f*d);
                anum += (double)(wgt*sd*sd);
                aden += (double)wgt;
                aslp += (double)logf(sigmoidf_(2.0f*sim) + 1e-8f);
                if (lane < 8) smsum += sj;
            } else {
                asln += (double)logf(sigmoidf_(-2.0f*sim) + 1e-8f);
            }
        }
        #pragma unroll
        for (int m = 32; m; m >>= 1) smsum += __shfl_xor(smsum, m, 64);
        if (lane == 0) {
            float dd = si - smsum*0.125f;
            asmo += (double)(dd*dd);
        }
    }
    __syncthreads();

    // ---- rare block-cooperative ladder fallback ----
    int nf = min((int)flnB, 64);
    u64* ovbuf = &wavebuf[0][0];    // 512 u64
    for (int f = 0; f < nf; ++f) {
        int fqg = (int)flistB[f];
        float4 fqc = P4s[fqg];
        float fsq = fqc.w;
        float fcov = 1e9f;
        float fqd[3] = {fqc.x, fqc.y, fqc.z};
        #pragma unroll
        for (int d = 0; d < 3; ++d) {
            if (!lw[d]) fcov = fminf(fcov, fqd[d] - lof[d]);
            if (!hw[d]) fcov = fminf(fcov, hif[d] - fqd[d]);
        }
        float fg2 = fcov*fcov;
        if (t < 6) cnt6[t] = 0;
        if (t == 0) { ovcnt = 0; smacc = 0.f; }
        __syncthreads();
        u32 c0=0,c1=0,c2=0,c3=0,c4=0,c5=0;
        for (int rr = 0; rr < nruns; ++rr) {
            for (int v = runsb[rr] + t; v < runse[rr]; v += 256) {
                float4 pp = P4s[v];
                float dot = fmaf(fqc.x, pp.x, fmaf(fqc.y, pp.y, fqc.z*pp.z));
                float e2 = fmaf(-2.0f, dot, pp.w);
                c0 += (e2 < TL0-fsq); c1 += (e2 < TL1-fsq); c2 += (e2 < TL2-fsq);
                c3 += (e2 < TL3-fsq); c4 += (e2 < TL4-fsq); c5 += (e2 < TL5-fsq);
            }
        }
        #pragma unroll
        for (int m = 32; m; m >>= 1) {
            c0 += __shfl_xor(c0, m, 64); c1 += __shfl_xor(c1, m, 64);
            c2 += __shfl_xor(c2, m, 64); c3 += __shfl_xor(c3, m, 64);
            c4 += __shfl_xor(c4, m, 64); c5 += __shfl_xor(c5, m, 64);
        }
        if (lane == 0) {
            atomicAdd(&cnt6[0], c0); atomicAdd(&cnt6[1], c1);
            atomicAdd(&cnt6[2], c2); atomicAdd(&cnt6[3], c3);
            atomicAdd(&cnt6[4], c4); atomicAdd(&cnt6[5], c5);
        }
        __syncthreads();
        float tau = TL2;
        if (TL3 <= fg2) tau = TL3;
        if (TL4 <= fg2) tau = TL4;
        if (TL5 <= fg2) tau = TL5;
        if      (cnt6[0] >= 32u) tau = TL0;
        else if (cnt6[1] >= 32u) tau = TL1;
        else if (cnt6[2] >= 32u) tau = TL2;
        else if (TL3 <= fg2 && cnt6[3] >= 32u) tau = TL3;
        else if (TL4 <= fg2 && cnt6[4] >= 32u) tau = TL4;
        else if (TL5 <= fg2 && cnt6[5] >= 32u) tau = TL5;
        float ftp = tau - fsq;
        for (int rr = 0; rr < nruns; ++rr) {
            for (int v = runsb[rr] + t; v < runse[rr]; v += 256) {
                float4 pp = P4s[v];
                float dot = fmaf(fqc.x, pp.x, fmaf(fqc.y, pp.y, fqc.z*pp.z));
                float e2 = fmaf(-2.0f, dot, pp.w);
                if (e2 < ftp) {
                    float d2 = fmaxf(e2 + fsq, 0.0f);
                    u64 key = ((u64)__float_as_uint(d2) << 13) | (u64)meta16[v];
                    u32 pos = atomicAdd(&ovcnt, 1u);
                    if (pos < 512u) ovbuf[pos] = key;
                }
            }
        }
        __syncthreads();
        u32 Mf = min(ovcnt, 512u);
        float fsi = S[sbase + (int)meta16[fqg]];
        for (int i = t; i < (int)Mf; i += 256) {
            u64 mykey = ovbuf[i];
            u32 rank = 0;
            for (u32 j = 0; j < Mf; ++j) rank += (ovbuf[j] < mykey);
            if (rank < 32u) {
                float d2 = __uint_as_float((u32)(mykey >> 13));
                u32 jo = (u32)(mykey & 0x1FFFu);
                float sj = S[sbase + (int)jo];
                float sd = fabsf(fsi - sj);
                float sim = 1.0f - sd;
                if (rank < 16u) {
                    float d = sqrtf(fmaxf(d2, 1e-24f));
                    float wgt = expf(-10.0f*d);
                    anum += (double)(wgt*sd*sd);
                    aden += (double)wgt;
                    aslp += (double)logf(sigmoidf_(2.0f*sim) + 1e-8f);
                    if (rank < 8u) atomicAdd(&smacc, sj);
                } else {
                    asln += (double)logf(sigmoidf_(-2.0f*sim) + 1e-8f);
                }
            }
        }
        __syncthreads();
        if (t == 0) {
            float dd = fsi - smacc*0.125f;
            asmo += (double)(dd*dd);
        }
        __syncthreads();
    }

    // ---- block reduce + global accumulate + fused final ----
    double v[5] = {anum, aden, aslp, asln, asmo};
    #pragma unroll
    for (int k = 0; k < 5; ++k) {
        for (int m = 32; m; m >>= 1) v[k] += __shfl_xor(v[k], m, 64);
    }
    if (lane == 0) {
        #pragma unroll
        for (int k = 0; k < 5; ++k) lred[w][k] = v[k];
    }
    __syncthreads();
    if (t == 0) {
        #pragma unroll
        for (int k = 0; k < 5; ++k)
            atomicAdd(&accum[k], lred[0][k] + lred[1][k] + lred[2][k] + lred[3][k]);
        __threadfence();
        u32 old = atomicAdd(donecnt, 1u);
        if (old == (u32)(NCELL_T - 1)) {
            double a0 = atomicAdd(&accum[0], 0.0);
            double a1 = atomicAdd(&accum[1], 0.0);
            double a2 = atomicAdd(&accum[2], 0.0);
            double a3 = atomicAdd(&accum[3], 0.0);
            double a4 = atomicAdd(&accum[4], 0.0);
            double loss_loc = a0 / fmax(a1, 1e-8);
            double inv = 1.0 / ((double)N_PTS * 16.0);
            double loss_con = -(a2 * inv) - (a3 * inv);
            double loss_sm = a4 / (double)N_PTS;
            out[0] = (float)(loss_loc + 0.5*loss_con + 0.2*loss_sm);
        }
    }
}

extern "C" void kernel_launch(void* const* d_in, const int* in_sizes, int n_in,
                              void* d_out, int out_size, void* d_ws, size_t ws_size,
                              hipStream_t stream) {
    const float* feat   = (const float*)d_in[0];
    const float* coords = (const float*)d_in[1];
    const float* W1 = (const float*)d_in[2];
    const float* b1 = (const float*)d_in[3];
    const float* g1 = (const float*)d_in[4];
    const float* be1= (const float*)d_in[5];
    const float* g2 = (const float*)d_in[8];
    const float* W2 = (const float*)d_in[6];
    const float* b2 = (const float*)d_in[7];
    const float* be2= (const float*)d_in[9];
    const float* W3 = (const float*)d_in[10];
    const float* b3 = (const float*)d_in[11];
    char* ws = (char*)d_ws;

    float* stats1   = (float*)(ws);
    float* stats2   = (float*)(ws + 512);
    u32* gcount     = (u32*)(ws + 1024);
    double* accum   = (double*)(ws + 4480);
    u32* donecnt    = (u32*)(ws + 4520);
    u32* cellstart  = (u32*)(ws + 4544);
    u32* cellptr    = (u32*)(ws + 8008);
    float* S        = (float*)(ws + 11472);
    float4* P4s     = (float4*)(ws + 142544);
    u16* meta16     = (u16*)(ws + 666832);
    u16* pcell      = (u16*)(ws + 732368);

    hipMemsetAsync(d_ws, 0, 4544, stream);

    hipLaunchKernelGGL(kA, dim3(NBLK), dim3(256), 0, stream,
                       feat, coords, W1, b1, gcount, pcell, stats1);
    hipLaunchKernelGGL(kB, dim3(NBLK), dim3(256), 0, stream,
                       feat, W1, b1, stats1, g1, be1, W2, b2,
                       gcount, cellstart, cellptr, stats2);
    hipLaunchKernelGGL(kC, dim3(NBLK), dim3(256), 0, stream,
                       feat, coords, W1, b1, stats1, g1, be1, W2, b2,
                       stats2, g2, be2, W3, b3, pcell, cellptr, P4s, meta16, S);
    hipLaunchKernelGGL(kD, dim3(NCELL_T), dim3(256), 0, stream,
                       P4s, meta16, cellstart, S, accum, donecnt, (float*)d_out);
}

// Round 9
// 325.599 us; speedup vs baseline: 2.3210x; 1.0639x over previous
//
#include <hip/hip_runtime.h>

typedef unsigned long long u64;
typedef unsigned int u32;
typedef unsigned short u16;

#define N_PTS 32768
#define M_PTS 8192
#define C_IN 6
#define H_DIM 64

#define G 6
#define NCELL 216
#define NCELL_T 864
#define CW (1.0f/3.0f)

#define NBLK 256
#define QG 4
#define KTGT 48.0f

#define TL0 0.0494f
#define TL1 0.0740f
#define TL2 0.1110f
#define TL3 0.1736f
#define TL4 0.2600f
#define TL5 0.4000f

// ws layout (bytes):
// 0      : stats1[128]f      (zeroed)
// 512    : stats2[128]f      (zeroed)
// 1024   : gcount[864]u32    (zeroed)  -> 4480
// 4480   : accum[5]double    (zeroed)  -> 4520
// 4520   : donecnt u32       (zeroed)  -> 4524 (memset 0..4544)
// 4544   : cellstart[865]u32 -> 8004 pad 8008
// 8008   : cellptr[864]u32   -> 11464 pad 11472
// 11472  : S[32768]f         -> 142544
// 142544 : P4s[32768]float4  -> 666832
// 666832 : meta16[32768]u16  -> 732368
// 732368 : pcell[32768]u16   -> 797904

__device__ __forceinline__ float gelu_exact(float x) {
    return 0.5f * x * (1.0f + erff(x * 0.70710678118654752f));
}
__device__ __forceinline__ float sigmoidf_(float x) {
    return 1.0f / (1.0f + expf(-x));
}
__device__ __forceinline__ u64 u64min_(u64 a, u64 b) { return a < b ? a : b; }
__device__ __forceinline__ u64 u64max_(u64 a, u64 b) { return a < b ? b : a; }

__device__ __forceinline__ u64 bitonic_sort64(u64 key, int lane) {
    #pragma unroll
    for (int k = 2; k <= 64; k <<= 1) {
        #pragma unroll
        for (int j = k >> 1; j; j >>= 1) {
            u64 pk = __shfl_xor(key, j, 64);
            bool up = ((lane & k) == 0);
            bool tmin = (((lane & j) == 0) == up);
            key = tmin ? u64min_(key, pk) : u64max_(key, pk);
        }
    }
    return key;
}

// ================= kA: cellpack + layer1 stats =================
__global__ __launch_bounds__(256) void kA(const float* __restrict__ feat,
        const float* __restrict__ coords, const float* __restrict__ W1,
        const float* __restrict__ b1, u32* __restrict__ gcount,
        u16* __restrict__ pcell, float* __restrict__ stats1) {
    __shared__ float red[512];
    int t = threadIdx.x, bid = blockIdx.x;
    if (bid < 128) {
        int n = bid * 256 + t;
        float x = coords[n*3], y = coords[n*3+1], z = coords[n*3+2];
        int cx = min(G-1, max(0, (int)floorf((x + 1.0f) * 3.0f)));
        int cy = min(G-1, max(0, (int)floorf((y + 1.0f) * 3.0f)));
        int cz = min(G-1, max(0, (int)floorf((z + 1.0f) * 3.0f)));
        int gcid = (n >> 13) * NCELL + (cz*G + cy)*G + cx;
        pcell[n] = (u16)gcid;
        atomicAdd(&gcount[gcid], 1u);
    }
    int c = t & 63, w = t >> 6;
    float w1c[C_IN];
    #pragma unroll
    for (int k = 0; k < C_IN; ++k) w1c[k] = W1[k*H_DIM + c];
    float bias = b1[c];
    float s1 = 0.f, s2 = 0.f;
    #pragma unroll 1
    for (int n = bid*8 + w*2; n < N_PTS; n += NBLK*8) {
        const float* fa = feat + n*C_IN;
        const float* fb = feat + (n+1)*C_IN;
        float ha = bias, hb = bias;
        #pragma unroll
        for (int k = 0; k < C_IN; ++k) {
            ha = fmaf(fa[k], w1c[k], ha);
            hb = fmaf(fb[k], w1c[k], hb);
        }
        s1 += ha + hb;
        s2 = fmaf(ha, ha, s2); s2 = fmaf(hb, hb, s2);
    }
    red[w*64 + c] = s1;
    red[256 + w*64 + c] = s2;
    __syncthreads();
    if (t < 64) {
        float a = red[t] + red[64+t] + red[128+t] + red[192+t];
        float b = red[256+t] + red[320+t] + red[384+t] + red[448+t];
        atomicAdd(&stats1[t], a);
        atomicAdd(&stats1[64+t], b);
    }
}

// ================= kB: scan (block 0) + layer2 stats =================
__global__ __launch_bounds__(256) void kB(const float* __restrict__ feat,
        const float* __restrict__ W1, const float* __restrict__ b1,
        const float* __restrict__ stats1, const float* __restrict__ g1,
        const float* __restrict__ be1, const float* __restrict__ W2,
        const float* __restrict__ b2, const u32* __restrict__ gcount,
        u32* __restrict__ cellstart, u32* __restrict__ cellptr,
        float* __restrict__ stats2) {
    __shared__ float red[512];
    __shared__ u32 sc[256];
    int t = threadIdx.x, bid = blockIdx.x;
    if (bid == 0) {
        u32 loc[4]; u32 s = 0;
        #pragma unroll
        for (int j = 0; j < 4; ++j) {
            int idx = t*4 + j;
            loc[j] = (idx < NCELL_T) ? gcount[idx] : 0u;
            s += loc[j];
        }
        sc[t] = s;
        __syncthreads();
        for (int off = 1; off < 256; off <<= 1) {
            u32 v = sc[t];
            if (t >= off) v += sc[t-off];
            __syncthreads();
            sc[t] = v;
            __syncthreads();
        }
        u32 run = sc[t] - s;
        #pragma unroll
        for (int j = 0; j < 4; ++j) {
            int idx = t*4 + j;
            if (idx < NCELL_T) { cellstart[idx] = run; cellptr[idx] = run; }
            run += loc[j];
        }
        if (t == 255) cellstart[NCELL_T] = sc[255];
        __syncthreads();
    }
    int c = t & 63, w = t >> 6;
    float w2c[H_DIM];
    #pragma unroll
    for (int k = 0; k < H_DIM; ++k) w2c[k] = W2[k*H_DIM + c];
    float w1c[C_IN];
    #pragma unroll
    for (int k = 0; k < C_IN; ++k) w1c[k] = W1[k*H_DIM + c];
    float mean1 = stats1[c] * (1.0f/N_PTS);
    float var1  = stats1[64+c] * (1.0f/N_PTS) - mean1*mean1;
    float sc1 = g1[c] * rsqrtf(var1 + 1e-5f);
    float sh1 = be1[c] - mean1*sc1;
    float bias1 = b1[c], bias2 = b2[c];
    float s1 = 0.f, s2 = 0.f;
    #pragma unroll 1
    for (int n = bid*8 + w*2; n < N_PTS; n += NBLK*8) {
        const float* fa = feat + n*C_IN;
        const float* fb = feat + (n+1)*C_IN;
        float ha = bias1, hb = bias1;
        #pragma unroll
        for (int k = 0; k < C_IN; ++k) {
            ha = fmaf(fa[k], w1c[k], ha);
            hb = fmaf(fb[k], w1c[k], hb);
        }
        float aa = gelu_exact(fmaf(sc1, ha, sh1));
        float ab = gelu_exact(fmaf(sc1, hb, sh1));
        float h2a = bias2, h2b = bias2;
        #pragma unroll
        for (int k = 0; k < H_DIM; ++k) {
            h2a = fmaf(__shfl(aa, k, 64), w2c[k], h2a);
            h2b = fmaf(__shfl(ab, k, 64), w2c[k], h2b);
        }
        s1 += h2a + h2b;
        s2 = fmaf(h2a, h2a, s2); s2 = fmaf(h2b, h2b, s2);
    }
    red[w*64 + c] = s1;
    red[256 + w*64 + c] = s2;
    __syncthreads();
    if (t < 64) {
        float a = red[t] + red[64+t] + red[128+t] + red[192+t];
        float b = red[256+t] + red[320+t] + red[384+t] + red[448+t];
        atomicAdd(&stats2[t], a);
        atomicAdd(&stats2[64+t], b);
    }
}

// ================= kC: scatter + score =================
__global__ __launch_bounds__(256) void kC(const float* __restrict__ feat,
        const float* __restrict__ coords,
        const float* __restrict__ W1, const float* __restrict__ b1,
        const float* __restrict__ stats1, const float* __restrict__ g1,
        const float* __restrict__ be1, const float* __restrict__ W2,
        const float* __restrict__ b2, const float* __restrict__ stats2,
        const float* __restrict__ g2v, const float* __restrict__ be2,
        const float* __restrict__ W3, const float* __restrict__ b3,
        const u16* __restrict__ pcell, u32* __restrict__ cellptr,
        float4* __restrict__ P4s, u16* __restrict__ meta16,
        float* __restrict__ S) {
    int t = threadIdx.x, bid = blockIdx.x;
    if (bid < 128) {
        int n = bid * 256 + t;
        float x = coords[n*3], y = coords[n*3+1], z = coords[n*3+2];
        float sq = fmaf(x, x, fmaf(y, y, z*z));
        u32 pos = atomicAdd(&cellptr[pcell[n]], 1u);
        P4s[pos] = make_float4(x, y, z, sq);
        meta16[pos] = (u16)(n & (M_PTS-1));
    }
    int c = t & 63, w = t >> 6;
    float w2c[H_DIM];
    #pragma unroll
    for (int k = 0; k < H_DIM; ++k) w2c[k] = W2[k*H_DIM + c];
    float w1c[C_IN];
    #pragma unroll
    for (int k = 0; k < C_IN; ++k) w1c[k] = W1[k*H_DIM + c];
    float mean1 = stats1[c] * (1.0f/N_PTS);
    float var1  = stats1[64+c] * (1.0f/N_PTS) - mean1*mean1;
    float sc1 = g1[c] * rsqrtf(var1 + 1e-5f);
    float sh1 = be1[c] - mean1*sc1;
    float mean2 = stats2[c] * (1.0f/N_PTS);
    float var2  = stats2[64+c] * (1.0f/N_PTS) - mean2*mean2;
    float sc2 = g2v[c] * rsqrtf(var2 + 1e-5f);
    float sh2 = be2[c] - mean2*sc2;
    float bias1 = b1[c], bias2 = b2[c], w3 = W3[c], bb = b3[0];
    #pragma unroll 1
    for (int n = bid*8 + w*2; n < N_PTS; n += NBLK*8) {
        const float* fa = feat + n*C_IN;
        const float* fb = feat + (n+1)*C_IN;
        float ha = bias1, hb = bias1;
        #pragma unroll
        for (int k = 0; k < C_IN; ++k) {
            ha = fmaf(fa[k], w1c[k], ha);
            hb = fmaf(fb[k], w1c[k], hb);
        }
        float aa = gelu_exact(fmaf(sc1, ha, sh1));
        float ab = gelu_exact(fmaf(sc1, hb, sh1));
        float h2a = bias2, h2b = bias2;
        #pragma unroll
        for (int k = 0; k < H_DIM; ++k) {
            h2a = fmaf(__shfl(aa, k, 64), w2c[k], h2a);
            h2b = fmaf(__shfl(ab, k, 64), w2c[k], h2b);
        }
        float a2a = gelu_exact(fmaf(sc2, h2a, sh2));
        float a2b = gelu_exact(fmaf(sc2, h2b, sh2));
        float va = a2a * w3, vb = a2b * w3;
        #pragma unroll
        for (int m = 32; m; m >>= 1) {
            va += __shfl_xor(va, m, 64);
            vb += __shfl_xor(vb, m, 64);
        }
        if (c == 0) {
            S[n] = sigmoidf_(va + bb);
            S[n+1] = sigmoidf_(vb + bb);
        }
    }
}

// ================= kD: KNN + losses + final (2 blocks/cell, 4 q/wave) =======
__global__ __launch_bounds__(256) void kD(const float4* __restrict__ P4s,
        const u16* __restrict__ meta16, const u32* __restrict__ cellstart,
        const float* __restrict__ S, double* __restrict__ accum,
        u32* __restrict__ donecnt, float* __restrict__ out) {
    __shared__ u64 wavebuf[4][QG][128];   // 16 KB
    __shared__ int runsb[16], runse[16];
    __shared__ int nruns_s;
    __shared__ u32 flistB[64];
    __shared__ u32 flnB;
    __shared__ u32 cnt6[6];
    __shared__ u32 ovcnt;
    __shared__ float smacc;
    __shared__ double lred[4][5];

    int t = threadIdx.x, bid = blockIdx.x;
    int lane = t & 63, w = t >> 6;
    u64 lmask = (1ull << lane) - 1ull;
    int cell = bid >> 1, half = bid & 1;
    int scene = cell / NCELL;
    int cid = cell - scene*NCELL;
    int cx = cid % G, cy = (cid / G) % G, cz = cid / (G*G);
    int sbase = scene * M_PTS;

    int ccrd[3] = {cx, cy, cz};
    bool wall[3]; int Wn = 0;
    #pragma unroll
    for (int d = 0; d < 3; ++d) { wall[d] = (ccrd[d] == 0 || ccrd[d] == G-1); Wn += wall[d]; }
    int lo[3], hi[3];
    #pragma unroll
    for (int d = 0; d < 3; ++d) {
        if (Wn >= 2 && !wall[d]) { lo[d] = min(max(ccrd[d]-2, 0), G-5); hi[d] = lo[d]+4; }
        else                     { lo[d] = min(max(ccrd[d]-1, 0), G-3); hi[d] = lo[d]+2; }
    }
    float lof[3], hif[3]; bool lw[3], hw[3];
    #pragma unroll
    for (int d = 0; d < 3; ++d) {
        lof[d] = -1.0f + lo[d]*CW; hif[d] = -1.0f + (hi[d]+1)*CW;
        lw[d] = (lo[d] == 0); hw[d] = (hi[d] == G-1);
    }
    if (t == 0) {
        int nr = 0;
        int nx = hi[0]-lo[0]+1;
        for (int z = lo[2]; z <= hi[2]; ++z)
            for (int y = lo[1]; y <= hi[1]; ++y) {
                int bc = scene*NCELL + (z*G + y)*G + lo[0];
                runsb[nr] = (int)cellstart[bc];
                runse[nr] = (int)cellstart[bc + nx];
                ++nr;
            }
        nruns_s = nr;
        flnB = 0;
    }
    int gcid = scene*NCELL + cid;
    int qstart = (int)cellstart[gcid];
    int qn = (int)cellstart[gcid+1] - qstart;
    __syncthreads();
    int nruns = nruns_s;
    int hq = (qn + 1) >> 1;
    int hqs = qstart + half * hq;
    int hqn = qn - half * hq; if (hqn > hq) hqn = hq; if (hqn < 0) hqn = 0;

    double anum=0.0, aden=0.0, aslp=0.0, asln=0.0, asmo=0.0;

    for (int g0 = w*QG; g0 < hqn; g0 += 4*QG) {
        int jcount = min(QG, hqn - g0);
        int qb = hqs + g0;
        float qx[QG], qy[QG], qz[QG], qs[QG], tp[QG];
        u32 baseq[QG];
        #pragma unroll
        for (int j = 0; j < QG; ++j) {
            int qg = qb + min(j, jcount-1);
            float4 qc = P4s[qg];
            qx[j]=qc.x; qy[j]=qc.y; qz[j]=qc.z; qs[j]=qc.w;
            float cov = 1e9f;
            float qdv[3] = {qc.x, qc.y, qc.z};
            #pragma unroll
            for (int d = 0; d < 3; ++d) {
                if (!lw[d]) cov = fminf(cov, qdv[d] - lof[d]);
                if (!hw[d]) cov = fminf(cov, hif[d] - qdv[d]);
            }
            float g2 = cov*cov;
            float axx = fminf(qc.x+1.f, 1.f-qc.x);
            float ayy = fminf(qc.y+1.f, 1.f-qc.y);
            float azz = fminf(qc.z+1.f, 1.f-qc.z);
            float r = 0.224f;
            #pragma unroll
            for (int it = 0; it < 3; ++it) {
                float ir = 1.0f / r;
                float ux = fminf(axx*ir, 1.f), uy = fminf(ayy*ir, 1.f), uz = fminf(azz*ir, 1.f);
                float fx = 0.25f*(2.f + 3.f*ux - ux*ux*ux);
                float fy = 0.25f*(2.f + 3.f*uy - uy*uy*uy);
                float fz = 0.25f*(2.f + 3.f*uz - uz*uz*uz);
                r = cbrtf(KTGT / (4289.32f * fx * fy * fz));
            }
            tp[j] = (j < jcount) ? (fminf(r*r, g2) - qc.w) : -1e30f;
            baseq[j] = 0;
        }

        // scan: unroll-2 loads, QG queries share each load
        for (int rr = 0; rr < nruns; ++rr) {
            int ve = runse[rr];
            for (int v0 = runsb[rr]; v0 < ve; v0 += 128) {
                int vA = v0 + lane, vB = v0 + 64 + lane;
                bool okA = vA < ve, okB = vB < ve;
                float4 pA = make_float4(0.f,0.f,0.f,1e30f);
                float4 pB = make_float4(0.f,0.f,0.f,1e30f);
                u32 mA = 0, mB = 0;
                if (okA) { pA = P4s[vA]; mA = (u32)meta16[vA]; }
                if (okB) { pB = P4s[vB]; mB = (u32)meta16[vB]; }
                #pragma unroll
                for (int j = 0; j < QG; ++j) {
                    float dotA = fmaf(qx[j], pA.x, fmaf(qy[j], pA.y, qz[j]*pA.z));
                    float e2A = fmaf(-2.0f, dotA, pA.w);
                    bool prA = okA && (e2A < tp[j]);
                    u64 mkA = __ballot(prA);
                    if (prA) {
                        float d2 = fmaxf(e2A + qs[j], 0.0f);
                        u64 key = ((u64)__float_as_uint(d2) << 13) | (u64)mA;
                        u32 pos = baseq[j] + (u32)__popcll(mkA & lmask);
                        if (pos < 128u) wavebuf[w][j][pos] = key;
                    }
                    baseq[j] += (u32)__popcll(mkA);
                    float dotB = fmaf(qx[j], pB.x, fmaf(qy[j], pB.y, qz[j]*pB.z));
                    float e2B = fmaf(-2.0f, dotB, pB.w);
                    bool prB = okB && (e2B < tp[j]);
                    u64 mkB = __ballot(prB);
                    if (prB) {
                        float d2 = fmaxf(e2B + qs[j], 0.0f);
                        u64 key = ((u64)__float_as_uint(d2) << 13) | (u64)mB;
                        u32 pos = baseq[j] + (u32)__popcll(mkB & lmask);
                        if (pos < 128u) wavebuf[w][j][pos] = key;
                    }
                    baseq[j] += (u32)__popcll(mkB);
                }
            }
        }

        // per-query sort + eval
        #pragma unroll
        for (int j = 0; j < QG; ++j) {
            if (j >= jcount) continue;
            int qg = qb + j;
            u32 M = baseq[j];
            if (M < 32u || M > 128u) {
                if (lane == 0) {
                    u32 idx = atomicAdd(&flnB, 1u);
                    if (idx < 64u) flistB[idx] = (u32)qg;
                }
                continue;
            }
            u64 k0 = (lane < (int)min(M, 64u)) ? wavebuf[w][j][lane] : ~0ull;
            k0 = bitonic_sort64(k0, lane);
            if (M > 64u) {
                u64 k1 = (lane < (int)(M - 64u)) ? wavebuf[w][j][64 + lane] : ~0ull;
                k1 = bitonic_sort64(k1, lane);
                u64 pk = __shfl(k1, 63 - lane, 64);
                u64 lo2 = u64min_(k0, pk);
                #pragma unroll
                for (int jj = 32; jj; jj >>= 1) {
                    u64 pj = __shfl_xor(lo2, jj, 64);
                    lo2 = ((lane & jj) == 0) ? u64min_(lo2, pj) : u64max_(lo2, pj);
                }
                k0 = lo2;
            }
            float si = S[sbase + (int)meta16[qg]];
            float smsum = 0.f;
            if (lane < 32) {
                float d2 = __uint_as_float((u32)(k0 >> 13));
                u32 jo = (u32)(k0 & 0x1FFFu);
                float sj = S[sbase + (int)jo];
                float sd = fabsf(si - sj);
                float sim = 1.0f - sd;
                if (lane < 16) {
                    float d = sqrtf(fmaxf(d2, 1e-24f));
                    float wgt = expf(-10.0f*d);
                    anum += (double)(wgt*sd*sd);
                    aden += (double)wgt;
                    aslp += (double)logf(sigmoidf_(2.0f*sim) + 1e-8f);
                    if (lane < 8) smsum += sj;
                } else {
                    asln += (double)logf(sigmoidf_(-2.0f*sim) + 1e-8f);
                }
            }
            #pragma unroll
            for (int m = 32; m; m >>= 1) smsum += __shfl_xor(smsum, m, 64);
            if (lane == 0) {
                float dd = si - smsum*0.125f;
                asmo += (double)(dd*dd);
            }
        }
    }
    __syncthreads();

    // ---- rare block-cooperative ladder fallback ----
    int nf = min((int)flnB, 64);
    u64* ovbuf = &wavebuf[0][0][0];    // 512 u64
    for (int f = 0; f < nf; ++f) {
        int fqg = (int)flistB[f];
        float4 fqc = P4s[fqg];
        float fsq = fqc.w;
        float fcov = 1e9f;
        float fqd[3] = {fqc.x, fqc.y, fqc.z};
        #pragma unroll
        for (int d = 0; d < 3; ++d) {
            if (!lw[d]) fcov = fminf(fcov, fqd[d] - lof[d]);
            if (!hw[d]) fcov = fminf(fcov, hif[d] - fqd[d]);
        }
        float fg2 = fcov*fcov;
        if (t < 6) cnt6[t] = 0;
        if (t == 0) { ovcnt = 0; smacc = 0.f; }
        __syncthreads();
        u32 c0=0,c1=0,c2=0,c3=0,c4=0,c5=0;
        for (int rr = 0; rr < nruns; ++rr) {
            for (int v = runsb[rr] + t; v < runse[rr]; v += 256) {
                float4 pp = P4s[v];
                float dot = fmaf(fqc.x, pp.x, fmaf(fqc.y, pp.y, fqc.z*pp.z));
                float e2 = fmaf(-2.0f, dot, pp.w);
                c0 += (e2 < TL0-fsq); c1 += (e2 < TL1-fsq); c2 += (e2 < TL2-fsq);
                c3 += (e2 < TL3-fsq); c4 += (e2 < TL4-fsq); c5 += (e2 < TL5-fsq);
            }
        }
        #pragma unroll
        for (int m = 32; m; m >>= 1) {
            c0 += __shfl_xor(c0, m, 64); c1 += __shfl_xor(c1, m, 64);
            c2 += __shfl_xor(c2, m, 64); c3 += __shfl_xor(c3, m, 64);
            c4 += __shfl_xor(c4, m, 64); c5 += __shfl_xor(c5, m, 64);
        }
        if (lane == 0) {
            atomicAdd(&cnt6[0], c0); atomicAdd(&cnt6[1], c1);
            atomicAdd(&cnt6[2], c2); atomicAdd(&cnt6[3], c3);
            atomicAdd(&cnt6[4], c4); atomicAdd(&cnt6[5], c5);
        }
        __syncthreads();
        float tau = TL2;
        if (TL3 <= fg2) tau = TL3;
        if (TL4 <= fg2) tau = TL4;
        if (TL5 <= fg2) tau = TL5;
        if      (cnt6[0] >= 32u) tau = TL0;
        else if (cnt6[1] >= 32u) tau = TL1;
        else if (cnt6[2] >= 32u) tau = TL2;
        else if (TL3 <= fg2 && cnt6[3] >= 32u) tau = TL3;
        else if (TL4 <= fg2 && cnt6[4] >= 32u) tau = TL4;
        else if (TL5 <= fg2 && cnt6[5] >= 32u) tau = TL5;
        float ftp = tau - fsq;
        for (int rr = 0; rr < nruns; ++rr) {
            for (int v = runsb[rr] + t; v < runse[rr]; v += 256) {
                float4 pp = P4s[v];
                float dot = fmaf(fqc.x, pp.x, fmaf(fqc.y, pp.y, fqc.z*pp.z));
                float e2 = fmaf(-2.0f, dot, pp.w);
                if (e2 < ftp) {
                    float d2 = fmaxf(e2 + fsq, 0.0f);
                    u64 key = ((u64)__float_as_uint(d2) << 13) | (u64)meta16[v];
                    u32 pos = atomicAdd(&ovcnt, 1u);
                    if (pos < 512u) ovbuf[pos] = key;
                }
            }
        }
        __syncthreads();
        u32 Mf = min(ovcnt, 512u);
        float fsi = S[sbase + (int)meta16[fqg]];
        for (int i = t; i < (int)Mf; i += 256) {
            u64 mykey = ovbuf[i];
            u32 rank = 0;
            for (u32 jj = 0; jj < Mf; ++jj) rank += (ovbuf[jj] < mykey);
            if (rank < 32u) {
                float d2 = __uint_as_float((u32)(mykey >> 13));
                u32 jo = (u32)(mykey & 0x1FFFu);
                float sj = S[sbase + (int)jo];
                float sd = fabsf(fsi - sj);
                float sim = 1.0f - sd;
                if (rank < 16u) {
                    float d = sqrtf(fmaxf(d2, 1e-24f));
                    float wgt = expf(-10.0f*d);
                    anum += (double)(wgt*sd*sd);
                    aden += (double)wgt;
                    aslp += (double)logf(sigmoidf_(2.0f*sim) + 1e-8f);
                    if (rank < 8u) atomicAdd(&smacc, sj);
                } else {
                    asln += (double)logf(sigmoidf_(-2.0f*sim) + 1e-8f);
                }
            }
        }
        __syncthreads();
        if (t == 0) {
            float dd = fsi - smacc*0.125f;
            asmo += (double)(dd*dd);
        }
        __syncthreads();
    }

    // ---- block reduce + global accumulate + fused final ----
    double v[5] = {anum, aden, aslp, asln, asmo};
    #pragma unroll
    for (int k = 0; k < 5; ++k) {
        for (int m = 32; m; m >>= 1) v[k] += __shfl_xor(v[k], m, 64);
    }
    if (lane == 0) {
        #pragma unroll
        for (int k = 0; k < 5; ++k) lred[w][k] = v[k];
    }
    __syncthreads();
    if (t == 0) {
        #pragma unroll
        for (int k = 0; k < 5; ++k)
            atomicAdd(&accum[k], lred[0][k] + lred[1][k] + lred[2][k] + lred[3][k]);
        __threadfence();
        u32 old = atomicAdd(donecnt, 1u);
        if (old == (u32)(2*NCELL_T - 1)) {
            double a0 = atomicAdd(&accum[0], 0.0);
            double a1 = atomicAdd(&accum[1], 0.0);
            double a2 = atomicAdd(&accum[2], 0.0);
            double a3 = atomicAdd(&accum[3], 0.0);
            double a4 = atomicAdd(&accum[4], 0.0);
            double loss_loc = a0 / fmax(a1, 1e-8);
            double inv = 1.0 / ((double)N_PTS * 16.0);
            double loss_con = -(a2 * inv) - (a3 * inv);
            double loss_sm = a4 / (double)N_PTS;
            out[0] = (float)(loss_loc + 0.5*loss_con + 0.2*loss_sm);
        }
    }
}

extern "C" void kernel_launch(void* const* d_in, const int* in_sizes, int n_in,
                              void* d_out, int out_size, void* d_ws, size_t ws_size,
                              hipStream_t stream) {
    const float* feat   = (const float*)d_in[0];
    const float* coords = (const float*)d_in[1];
    const float* W1 = (const float*)d_in[2];
    const float* b1 = (const float*)d_in[3];
    const float* g1 = (const float*)d_in[4];
    const float* be1= (const float*)d_in[5];
    const float* W2 = (const float*)d_in[6];
    const float* b2 = (const float*)d_in[7];
    const float* g2 = (const float*)d_in[8];
    const float* be2= (const float*)d_in[9];
    const float* W3 = (const float*)d_in[10];
    const float* b3 = (const float*)d_in[11];
    char* ws = (char*)d_ws;

    float* stats1   = (float*)(ws);
    float* stats2   = (float*)(ws + 512);
    u32* gcount     = (u32*)(ws + 1024);
    double* accum   = (double*)(ws + 4480);
    u32* donecnt    = (u32*)(ws + 4520);
    u32* cellstart  = (u32*)(ws + 4544);
    u32* cellptr    = (u32*)(ws + 8008);
    float* S        = (float*)(ws + 11472);
    float4* P4s     = (float4*)(ws + 142544);
    u16* meta16     = (u16*)(ws + 666832);
    u16* pcell      = (u16*)(ws + 732368);

    hipMemsetAsync(d_ws, 0, 4544, stream);

    hipLaunchKernelGGL(kA, dim3(NBLK), dim3(256), 0, stream,
                       feat, coords, W1, b1, gcount, pcell, stats1);
    hipLaunchKernelGGL(kB, dim3(NBLK), dim3(256), 0, stream,
                       feat, W1, b1, stats1, g1, be1, W2, b2,
                       gcount, cellstart, cellptr, stats2);
    hipLaunchKernelGGL(kC, dim3(NBLK), dim3(256), 0, stream,
                       feat, coords, W1, b1, stats1, g1, be1, W2, b2,
                       stats2, g2, be2, W3, b3, pcell, cellptr, P4s, meta16, S);
    hipLaunchKernelGGL(kD, dim3(2*NCELL_T), dim3(256), 0, stream,
                       P4s, meta16, cellstart, S, accum, donecnt, (float*)d_out);
}